// Round 1
// baseline (4053.947 us; speedup 1.0000x reference)
//
#include <hip/hip_runtime.h>
#include <math.h>

#define BB 64
#define PP 80
#define LC 18
#define EE 256
#define HH 1024
#define LCH 4
#define KW 3
#define TAGS 50
#define DD 260          // EE + LCH
#define ROWS (BB*PP)    // 5120
#define WN (LC-KW+1)    // 16

__device__ __forceinline__ float wave_reduce_sum(float v) {
    for (int off = 32; off > 0; off >>= 1) v += __shfl_xor(v, off, 64);
    return v;
}

// ---------------- embedding + char CNN ----------------
// one block per combined-row r (r = b*80 + p)
__global__ __launch_bounds__(256) void embed_kernel(
    const int* __restrict__ sent, const int* __restrict__ chars,
    const float* __restrict__ word_emb, const float* __restrict__ char_emb,
    const float* __restrict__ conv_w, const float* __restrict__ conv_b,
    float* __restrict__ combined)
{
    __shared__ float4 ce[LC * 64];      // [18][256] floats as float4
    __shared__ float phi[WN * LCH];
    __shared__ float charrep[LCH];
    const int r = blockIdx.x;
    const int t = threadIdx.x;
    const int lane = t & 63, wv = t >> 6;

    // stage char embeddings (18*64 float4 = 1152, 256 threads -> 5 iters)
    const int cbase = r * LC;
    for (int i = 0; i < 5; ++i) {
        int idx = i * 256 + t;
        if (idx < LC * 64) {
            int j = idx >> 6, e4 = idx & 63;
            int ch = chars[cbase + j];
            ce[idx] = ((const float4*)(char_emb + (size_t)ch * EE))[e4];
        }
    }
    // conv_w per-lane slice in registers: lane owns e = lane*4..lane*4+3 for each (k,c)
    float4 cw[KW][LCH];
    #pragma unroll
    for (int k = 0; k < KW; ++k)
        #pragma unroll
        for (int c = 0; c < LCH; ++c)
            cw[k][c] = ((const float4*)(conv_w + c * (KW * EE) + k * EE))[lane];
    __syncthreads();

    // wave wv handles windows wv, wv+4, wv+8, wv+12
    #pragma unroll
    for (int wi = 0; wi < 4; ++wi) {
        int w = wv + wi * 4;
        float acc[LCH] = {0.f, 0.f, 0.f, 0.f};
        #pragma unroll
        for (int k = 0; k < KW; ++k) {
            float4 v = ce[(w + k) * 64 + lane];
            #pragma unroll
            for (int c = 0; c < LCH; ++c)
                acc[c] += v.x * cw[k][c].x + v.y * cw[k][c].y +
                          v.z * cw[k][c].z + v.w * cw[k][c].w;
        }
        #pragma unroll
        for (int c = 0; c < LCH; ++c) {
            float s = wave_reduce_sum(acc[c]);
            if (lane == 0) phi[w * LCH + c] = s;
        }
    }
    __syncthreads();
    if (t < LCH) {
        float m = -1e30f;
        for (int w = 0; w < WN; ++w) m = fmaxf(m, phi[w * LCH + t]);
        charrep[t] = m + conv_b[t];
    }
    __syncthreads();

    const int word = sent[r];
    combined[(size_t)r * DD + t] = word_emb[(size_t)word * EE + t];
    if (t < LCH) combined[(size_t)r * DD + EE + t] = charrep[t];
}

// ---------------- one LSTM time step ----------------
// grid 256 blocks x 256 threads: thread = (b = tid&63, u = blk*4 + tid>>6)
// computes i,f,g,o dots (K = 260 + 1024) and the c/h update for its (b,u).
__global__ __launch_bounds__(256) void lstm_step(
    const float* __restrict__ combined,
    const float* __restrict__ w_ih, const float* __restrict__ w_hh,
    const float* __restrict__ b_ih, const float* __restrict__ b_hh,
    float* __restrict__ hs, float* __restrict__ c_state, int t)
{
    const int tid = threadIdx.x;
    const int b = tid & 63;
    const int u = __builtin_amdgcn_readfirstlane(blockIdx.x * 4 + (tid >> 6));

    const float4* xrow = (const float4*)(combined + (size_t)(t * BB + b) * DD);
    const float4* wi0 = (const float4*)(w_ih + (size_t)(u          ) * DD);
    const float4* wi1 = (const float4*)(w_ih + (size_t)(u +     HH) * DD);
    const float4* wi2 = (const float4*)(w_ih + (size_t)(u + 2 * HH) * DD);
    const float4* wi3 = (const float4*)(w_ih + (size_t)(u + 3 * HH) * DD);

    float a0 = 0.f, a1 = 0.f, a2 = 0.f, a3 = 0.f;
    #pragma unroll 4
    for (int d = 0; d < DD / 4; ++d) {
        float4 x = xrow[d];
        float4 v;
        v = wi0[d]; a0 += x.x * v.x + x.y * v.y + x.z * v.z + x.w * v.w;
        v = wi1[d]; a1 += x.x * v.x + x.y * v.y + x.z * v.z + x.w * v.w;
        v = wi2[d]; a2 += x.x * v.x + x.y * v.y + x.z * v.z + x.w * v.w;
        v = wi3[d]; a3 += x.x * v.x + x.y * v.y + x.z * v.z + x.w * v.w;
    }
    if (t > 0) {
        const float4* hrow = (const float4*)(hs + (size_t)((t - 1) * BB + b) * HH);
        const float4* wh0 = (const float4*)(w_hh + (size_t)(u          ) * HH);
        const float4* wh1 = (const float4*)(w_hh + (size_t)(u +     HH) * HH);
        const float4* wh2 = (const float4*)(w_hh + (size_t)(u + 2 * HH) * HH);
        const float4* wh3 = (const float4*)(w_hh + (size_t)(u + 3 * HH) * HH);
        #pragma unroll 4
        for (int j = 0; j < HH / 4; ++j) {
            float4 h = hrow[j];
            float4 v;
            v = wh0[j]; a0 += h.x * v.x + h.y * v.y + h.z * v.z + h.w * v.w;
            v = wh1[j]; a1 += h.x * v.x + h.y * v.y + h.z * v.z + h.w * v.w;
            v = wh2[j]; a2 += h.x * v.x + h.y * v.y + h.z * v.z + h.w * v.w;
            v = wh3[j]; a3 += h.x * v.x + h.y * v.y + h.z * v.z + h.w * v.w;
        }
    }
    float gi = a0 + b_ih[u]          + b_hh[u];
    float gf = a1 + b_ih[u +     HH] + b_hh[u +     HH];
    float gg = a2 + b_ih[u + 2 * HH] + b_hh[u + 2 * HH];
    float go = a3 + b_ih[u + 3 * HH] + b_hh[u + 3 * HH];
    gi = 1.f / (1.f + __expf(-gi));
    gf = 1.f / (1.f + __expf(-gf));
    gg = tanhf(gg);
    go = 1.f / (1.f + __expf(-go));
    float cp = (t > 0) ? c_state[u * BB + b] : 0.f;
    float cn = gf * cp + gi * gg;
    float hn = go * tanhf(cn);
    c_state[u * BB + b] = cn;
    hs[(size_t)(t * BB + b) * HH + u] = hn;
}

// ---------------- tag head ----------------
// 80 blocks x 256 threads: thread = (rr = blk*64 + lane, wave wv owns tags wv+4i)
__global__ __launch_bounds__(256) void tag_kernel(
    const float* __restrict__ hs, const float* __restrict__ out_w,
    const float* __restrict__ out_b, float* __restrict__ out)
{
    const int tid = threadIdx.x;
    const int rr = blockIdx.x * 64 + (tid & 63);
    const int wv = __builtin_amdgcn_readfirstlane(tid >> 6);
    float acc[13];
    #pragma unroll
    for (int i = 0; i < 13; ++i) acc[i] = 0.f;
    const float4* hrow = (const float4*)(hs + (size_t)rr * HH);
    for (int j = 0; j < HH / 4; ++j) {
        float4 h = hrow[j];
        #pragma unroll
        for (int i = 0; i < 13; ++i) {
            int g = wv + i * 4;
            if (g < TAGS) {
                float4 v = ((const float4*)(out_w + (size_t)g * HH))[j];
                acc[i] += h.x * v.x + h.y * v.y + h.z * v.z + h.w * v.w;
            }
        }
    }
    #pragma unroll
    for (int i = 0; i < 13; ++i) {
        int g = wv + i * 4;
        if (g < TAGS) out[(size_t)rr * TAGS + g] = acc[i] + out_b[g];
    }
}

// ---------------- log_softmax over the P axis, in place ----------------
// one wave per (b, tag) pair
__global__ __launch_bounds__(256) void logsoftmax_kernel(float* __restrict__ out)
{
    const int tid = threadIdx.x;
    const int lane = tid & 63;
    const int pair = blockIdx.x * 4 + (tid >> 6);
    if (pair >= BB * TAGS) return;
    const int bb = pair / TAGS, g = pair % TAGS;
    float* base = out + (size_t)bb * PP * TAGS + g;
    float v0 = base[lane * TAGS];
    float v1 = (lane < PP - 64) ? base[(lane + 64) * TAGS] : -1e30f;
    float m = fmaxf(v0, v1);
    for (int off = 32; off > 0; off >>= 1) m = fmaxf(m, __shfl_xor(m, off, 64));
    float s = __expf(v0 - m) + ((lane < PP - 64) ? __expf(v1 - m) : 0.f);
    s = wave_reduce_sum(s);
    float lz = m + __logf(s);
    base[lane * TAGS] = v0 - lz;
    if (lane < PP - 64) base[(lane + 64) * TAGS] = v1 - lz;
}

extern "C" void kernel_launch(void* const* d_in, const int* in_sizes, int n_in,
                              void* d_out, int out_size, void* d_ws, size_t ws_size,
                              hipStream_t stream)
{
    const int*   sent     = (const int*)d_in[0];
    const int*   chars    = (const int*)d_in[1];
    const float* word_emb = (const float*)d_in[2];
    const float* char_emb = (const float*)d_in[3];
    const float* conv_w   = (const float*)d_in[4];
    const float* conv_b   = (const float*)d_in[5];
    const float* w_ih     = (const float*)d_in[6];
    const float* w_hh     = (const float*)d_in[7];
    const float* b_ih     = (const float*)d_in[8];
    const float* b_hh     = (const float*)d_in[9];
    const float* out_w    = (const float*)d_in[10];
    const float* out_b    = (const float*)d_in[11];
    float* out = (float*)d_out;

    float* combined = (float*)d_ws;                          // 5120*260 f32
    float* hs       = combined + (size_t)ROWS * DD;          // 5120*1024 f32
    float* c_state  = hs + (size_t)ROWS * HH;                // 1024*64 f32

    hipLaunchKernelGGL(embed_kernel, dim3(ROWS), dim3(256), 0, stream,
                       sent, chars, word_emb, char_emb, conv_w, conv_b, combined);
    for (int t = 0; t < PP; ++t)
        hipLaunchKernelGGL(lstm_step, dim3(HH / 4), dim3(256), 0, stream,
                           combined, w_ih, w_hh, b_ih, b_hh, hs, c_state, t);
    hipLaunchKernelGGL(tag_kernel, dim3(ROWS / 64), dim3(256), 0, stream,
                       hs, out_w, out_b, out);
    hipLaunchKernelGGL(logsoftmax_kernel, dim3((BB * TAGS + 3) / 4), dim3(256), 0, stream,
                       out);
}

// Round 2
// 1920.649 us; speedup vs baseline: 2.1107x; 2.1107x over previous
//
#include <hip/hip_runtime.h>
#include <math.h>

#define BB 64
#define PP 80
#define LC 18
#define EE 256
#define HH 1024
#define LCH 4
#define KW 3
#define TAGS 50
#define DD 260          // EE + LCH
#define KPAD 288        // DD padded to multiple of 32
#define ROWS (BB*PP)    // 5120
#define WN (LC-KW+1)    // 16
#define NG (4*HH)       // 4096 gate rows

typedef __attribute__((ext_vector_type(8))) short short8;   // 8 x bf16
typedef __attribute__((ext_vector_type(4))) float floatx4;  // MFMA acc

__device__ __forceinline__ short f2bf(float x) {
    unsigned u = __float_as_uint(x);
    unsigned r = (u + 0x7FFFu + ((u >> 16) & 1u)) >> 16;
    return (short)r;
}
__device__ __forceinline__ float bf2f(short s) {
    return __uint_as_float(((unsigned)(unsigned short)s) << 16);
}
__device__ __forceinline__ float wave_reduce_sum(float v) {
    for (int off = 32; off > 0; off >>= 1) v += __shfl_xor(v, off, 64);
    return v;
}

// ---------------- weight prep: fp32 -> bf16 (+padding), zero h_{-1} ----------
__global__ __launch_bounds__(256) void prep_kernel(
    const float* __restrict__ wih, const float* __restrict__ whh,
    const float* __restrict__ outw,
    short* __restrict__ wih_bf, short* __restrict__ whh_bf,
    short* __restrict__ outw_bf, short* __restrict__ hs0)
{
    const int NI = NG * KPAD;       // 1179648
    const int NH = NG * HH;         // 4194304
    const int NO = 64 * HH;         // 65536 (out_w padded to 64 rows)
    const int NZ = BB * HH;         // 65536 (h_{-1} zeros)
    const int total = NI + NH + NO + NZ;
    for (int i = blockIdx.x * 256 + threadIdx.x; i < total; i += gridDim.x * 256) {
        if (i < NI) {
            int r = i / KPAD, c = i - r * KPAD;
            wih_bf[i] = (c < DD) ? f2bf(wih[r * DD + c]) : (short)0;
        } else if (i < NI + NH) {
            int j = i - NI;
            whh_bf[j] = f2bf(whh[j]);
        } else if (i < NI + NH + NO) {
            int k = i - NI - NH;
            int r = k >> 10;
            outw_bf[k] = (r < TAGS) ? f2bf(outw[k]) : (short)0;
        } else {
            hs0[i - NI - NH - NO] = (short)0;
        }
    }
}

// ---------------- embedding + char CNN -> X bf16 [5120][288] ----------------
__global__ __launch_bounds__(256) void embed_kernel(
    const int* __restrict__ sent, const int* __restrict__ chars,
    const float* __restrict__ word_emb, const float* __restrict__ char_emb,
    const float* __restrict__ conv_w, const float* __restrict__ conv_b,
    short* __restrict__ X)
{
    __shared__ float4 ce[LC * 64];
    __shared__ float phi[WN * LCH];
    __shared__ float charrep[LCH];
    const int r = blockIdx.x;
    const int t = threadIdx.x;
    const int lane = t & 63, wv = t >> 6;

    const int cbase = r * LC;
    for (int i = 0; i < 5; ++i) {
        int idx = i * 256 + t;
        if (idx < LC * 64) {
            int j = idx >> 6, e4 = idx & 63;
            int ch = chars[cbase + j];
            ce[idx] = ((const float4*)(char_emb + (size_t)ch * EE))[e4];
        }
    }
    float4 cw[KW][LCH];
    #pragma unroll
    for (int k = 0; k < KW; ++k)
        #pragma unroll
        for (int c = 0; c < LCH; ++c)
            cw[k][c] = ((const float4*)(conv_w + c * (KW * EE) + k * EE))[lane];
    __syncthreads();

    #pragma unroll
    for (int wi = 0; wi < 4; ++wi) {
        int w = wv + wi * 4;
        float acc[LCH] = {0.f, 0.f, 0.f, 0.f};
        #pragma unroll
        for (int k = 0; k < KW; ++k) {
            float4 v = ce[(w + k) * 64 + lane];
            #pragma unroll
            for (int c = 0; c < LCH; ++c)
                acc[c] += v.x * cw[k][c].x + v.y * cw[k][c].y +
                          v.z * cw[k][c].z + v.w * cw[k][c].w;
        }
        #pragma unroll
        for (int c = 0; c < LCH; ++c) {
            float s = wave_reduce_sum(acc[c]);
            if (lane == 0) phi[w * LCH + c] = s;
        }
    }
    __syncthreads();
    if (t < LCH) {
        float m = -1e30f;
        for (int w = 0; w < WN; ++w) m = fmaxf(m, phi[w * LCH + t]);
        charrep[t] = m + conv_b[t];
    }
    __syncthreads();

    const int word = sent[r];
    X[(size_t)r * KPAD + t] = f2bf(word_emb[(size_t)word * EE + t]);
    if (t < LCH) X[(size_t)r * KPAD + EE + t] = f2bf(charrep[t]);
    if (t >= 228) X[(size_t)r * KPAD + 32 + t] = (short)0;   // cols 260..287 = 0
}

// ---------------- input GEMM: ginT[n][r] = X[r]·w_ih[n] + b_ih[n]+b_hh[n] ----
// block 256 thr (4 waves), tile M64 x N128 (wave: 64x32), K = 288
__global__ __launch_bounds__(256) void gemm_in_kernel(
    const short* __restrict__ X, const short* __restrict__ Wih,
    const float* __restrict__ b_ih, const float* __restrict__ b_hh,
    short* __restrict__ ginT)
{
    const int tid = threadIdx.x;
    const int l = tid & 63, wv = tid >> 6;
    const int r0 = blockIdx.x * 64;
    const int n0 = blockIdx.y * 128 + wv * 32;
    const int lr = l & 15, lk = (l >> 4) * 8;

    floatx4 acc[4][2];
    #pragma unroll
    for (int m = 0; m < 4; ++m)
        #pragma unroll
        for (int n = 0; n < 2; ++n) acc[m][n] = (floatx4)0.f;

    const short* Xb = X + (size_t)(r0 + lr) * KPAD + lk;
    const short* Wb = Wih + (size_t)(n0 + lr) * KPAD + lk;

    #pragma unroll
    for (int k0 = 0; k0 < KPAD; k0 += 32) {
        short8 a0 = *(const short8*)(Xb + k0);
        short8 a1 = *(const short8*)(Xb + 16 * KPAD + k0);
        short8 a2 = *(const short8*)(Xb + 32 * KPAD + k0);
        short8 a3 = *(const short8*)(Xb + 48 * KPAD + k0);
        short8 b0 = *(const short8*)(Wb + k0);
        short8 b1 = *(const short8*)(Wb + 16 * KPAD + k0);
        acc[0][0] = __builtin_amdgcn_mfma_f32_16x16x32_bf16(a0, b0, acc[0][0], 0, 0, 0);
        acc[1][0] = __builtin_amdgcn_mfma_f32_16x16x32_bf16(a1, b0, acc[1][0], 0, 0, 0);
        acc[2][0] = __builtin_amdgcn_mfma_f32_16x16x32_bf16(a2, b0, acc[2][0], 0, 0, 0);
        acc[3][0] = __builtin_amdgcn_mfma_f32_16x16x32_bf16(a3, b0, acc[3][0], 0, 0, 0);
        acc[0][1] = __builtin_amdgcn_mfma_f32_16x16x32_bf16(a0, b1, acc[0][1], 0, 0, 0);
        acc[1][1] = __builtin_amdgcn_mfma_f32_16x16x32_bf16(a1, b1, acc[1][1], 0, 0, 0);
        acc[2][1] = __builtin_amdgcn_mfma_f32_16x16x32_bf16(a2, b1, acc[2][1], 0, 0, 0);
        acc[3][1] = __builtin_amdgcn_mfma_f32_16x16x32_bf16(a3, b1, acc[3][1], 0, 0, 0);
    }
    #pragma unroll
    for (int m = 0; m < 4; ++m)
        #pragma unroll
        for (int n = 0; n < 2; ++n) {
            int col = n0 + n * 16 + lr;
            float bias = b_ih[col] + b_hh[col];
            #pragma unroll
            for (int q = 0; q < 4; ++q) {
                int row = r0 + m * 16 + (l >> 4) * 4 + q;
                ginT[(size_t)col * ROWS + row] = f2bf(acc[m][n][q] + bias);
            }
        }
}

// ---------------- one LSTM step: R = h_{t-1}·w_hh^T, fused gate update -------
// 64 blocks x 256 thr; block owns units u0..u0+15; wave g computes gate g tile
__global__ __launch_bounds__(256) void lstm_step_kernel(
    short* __restrict__ hs, const short* __restrict__ Whh,
    const short* __restrict__ ginT, float* __restrict__ c_state, int t)
{
    __shared__ float lds[4][64][17];
    const int tid = threadIdx.x;
    const int l = tid & 63, g = tid >> 6;
    const int u0 = blockIdx.x * 16;
    const int lr = l & 15, lk = (l >> 4) * 8;

    const short* A = hs + (size_t)(t * BB + lr) * HH + lk;          // h_{t-1}
    const short* Bw = Whh + (size_t)(g * HH + u0 + lr) * HH + lk;

    floatx4 acc[4];
    #pragma unroll
    for (int m = 0; m < 4; ++m) acc[m] = (floatx4)0.f;

    #pragma unroll 4
    for (int k0 = 0; k0 < HH; k0 += 32) {
        short8 b  = *(const short8*)(Bw + k0);
        short8 a0 = *(const short8*)(A + k0);
        short8 a1 = *(const short8*)(A + 16 * HH + k0);
        short8 a2 = *(const short8*)(A + 32 * HH + k0);
        short8 a3 = *(const short8*)(A + 48 * HH + k0);
        acc[0] = __builtin_amdgcn_mfma_f32_16x16x32_bf16(a0, b, acc[0], 0, 0, 0);
        acc[1] = __builtin_amdgcn_mfma_f32_16x16x32_bf16(a1, b, acc[1], 0, 0, 0);
        acc[2] = __builtin_amdgcn_mfma_f32_16x16x32_bf16(a2, b, acc[2], 0, 0, 0);
        acc[3] = __builtin_amdgcn_mfma_f32_16x16x32_bf16(a3, b, acc[3], 0, 0, 0);
    }
    #pragma unroll
    for (int m = 0; m < 4; ++m)
        #pragma unroll
        for (int q = 0; q < 4; ++q)
            lds[g][m * 16 + (l >> 4) * 4 + q][lr] = acc[m][q];
    __syncthreads();

    #pragma unroll
    for (int j = 0; j < 4; ++j) {
        int lid = tid + j * 256;
        int b = lid & 63, ul = lid >> 6;
        int u = u0 + ul;
        int r4 = t * BB + b;
        float gi_ = lds[0][b][ul] + bf2f(ginT[(size_t)(u)            * ROWS + r4]);
        float gf_ = lds[1][b][ul] + bf2f(ginT[(size_t)(HH + u)       * ROWS + r4]);
        float gg_ = lds[2][b][ul] + bf2f(ginT[(size_t)(2 * HH + u)   * ROWS + r4]);
        float go_ = lds[3][b][ul] + bf2f(ginT[(size_t)(3 * HH + u)   * ROWS + r4]);
        gi_ = 1.f / (1.f + __expf(-gi_));
        gf_ = 1.f / (1.f + __expf(-gf_));
        gg_ = tanhf(gg_);
        go_ = 1.f / (1.f + __expf(-go_));
        float cp = (t > 0) ? c_state[u * BB + b] : 0.f;
        float cn = gf_ * cp + gi_ * gg_;
        float hn = go_ * tanhf(cn);
        c_state[u * BB + b] = cn;
        hs[(size_t)((t + 1) * BB + b) * HH + u] = f2bf(hn);
    }
}

// ---------------- tag head: out = hs·out_w^T + out_b (MFMA) ------------------
// 80 blocks x 4 waves; wave wv: N-tile n0 = wv*16 (out_w padded to 64 rows)
__global__ __launch_bounds__(256) void tag_kernel(
    const short* __restrict__ hs, const short* __restrict__ outw_bf,
    const float* __restrict__ out_b, float* __restrict__ out)
{
    const int tid = threadIdx.x;
    const int l = tid & 63, wv = tid >> 6;
    const int r0 = blockIdx.x * 64;
    const int n0 = wv * 16;
    const int lr = l & 15, lk = (l >> 4) * 8;

    const short* A = hs + (size_t)(BB + r0 + lr) * HH + lk;   // skip h_{-1} block
    const short* Bw = outw_bf + (size_t)(n0 + lr) * HH + lk;

    floatx4 acc[4];
    #pragma unroll
    for (int m = 0; m < 4; ++m) acc[m] = (floatx4)0.f;

    #pragma unroll 4
    for (int k0 = 0; k0 < HH; k0 += 32) {
        short8 b  = *(const short8*)(Bw + k0);
        short8 a0 = *(const short8*)(A + k0);
        short8 a1 = *(const short8*)(A + 16 * HH + k0);
        short8 a2 = *(const short8*)(A + 32 * HH + k0);
        short8 a3 = *(const short8*)(A + 48 * HH + k0);
        acc[0] = __builtin_amdgcn_mfma_f32_16x16x32_bf16(a0, b, acc[0], 0, 0, 0);
        acc[1] = __builtin_amdgcn_mfma_f32_16x16x32_bf16(a1, b, acc[1], 0, 0, 0);
        acc[2] = __builtin_amdgcn_mfma_f32_16x16x32_bf16(a2, b, acc[2], 0, 0, 0);
        acc[3] = __builtin_amdgcn_mfma_f32_16x16x32_bf16(a3, b, acc[3], 0, 0, 0);
    }
    int col = n0 + lr;
    if (col < TAGS) {
        float bias = out_b[col];
        #pragma unroll
        for (int m = 0; m < 4; ++m)
            #pragma unroll
            for (int q = 0; q < 4; ++q) {
                int row = r0 + m * 16 + (l >> 4) * 4 + q;
                out[(size_t)row * TAGS + col] = acc[m][q] + bias;
            }
    }
}

// ---------------- log_softmax over the P axis, in place ----------------------
__global__ __launch_bounds__(256) void logsoftmax_kernel(float* __restrict__ out)
{
    const int tid = threadIdx.x;
    const int lane = tid & 63;
    const int pair = blockIdx.x * 4 + (tid >> 6);
    if (pair >= BB * TAGS) return;
    const int bb = pair / TAGS, g = pair % TAGS;
    float* base = out + (size_t)bb * PP * TAGS + g;
    float v0 = base[lane * TAGS];
    float v1 = (lane < PP - 64) ? base[(lane + 64) * TAGS] : -1e30f;
    float m = fmaxf(v0, v1);
    for (int off = 32; off > 0; off >>= 1) m = fmaxf(m, __shfl_xor(m, off, 64));
    float s = __expf(v0 - m) + ((lane < PP - 64) ? __expf(v1 - m) : 0.f);
    s = wave_reduce_sum(s);
    float lz = m + __logf(s);
    base[lane * TAGS] = v0 - lz;
    if (lane < PP - 64) base[(lane + 64) * TAGS] = v1 - lz;
}

extern "C" void kernel_launch(void* const* d_in, const int* in_sizes, int n_in,
                              void* d_out, int out_size, void* d_ws, size_t ws_size,
                              hipStream_t stream)
{
    const int*   sent     = (const int*)d_in[0];
    const int*   chars    = (const int*)d_in[1];
    const float* word_emb = (const float*)d_in[2];
    const float* char_emb = (const float*)d_in[3];
    const float* conv_w   = (const float*)d_in[4];
    const float* conv_b   = (const float*)d_in[5];
    const float* w_ih     = (const float*)d_in[6];
    const float* w_hh     = (const float*)d_in[7];
    const float* b_ih     = (const float*)d_in[8];
    const float* b_hh     = (const float*)d_in[9];
    const float* out_w    = (const float*)d_in[10];
    const float* out_b    = (const float*)d_in[11];
    float* out = (float*)d_out;

    short* X_bf    = (short*)d_ws;                             // 5120*288
    short* wih_bf  = X_bf + (size_t)ROWS * KPAD;               // 4096*288
    short* whh_bf  = wih_bf + (size_t)NG * KPAD;               // 4096*1024
    short* outw_bf = whh_bf + (size_t)NG * HH;                 // 64*1024
    short* ginT    = outw_bf + (size_t)64 * HH;                // 4096*5120
    short* hs_bf   = ginT + (size_t)NG * ROWS;                 // 81*64*1024
    float* c_state = (float*)(hs_bf + (size_t)(PP + 1) * BB * HH); // 1024*64

    hipLaunchKernelGGL(prep_kernel, dim3(2048), dim3(256), 0, stream,
                       w_ih, w_hh, out_w, wih_bf, whh_bf, outw_bf, hs_bf);
    hipLaunchKernelGGL(embed_kernel, dim3(ROWS), dim3(256), 0, stream,
                       sent, chars, word_emb, char_emb, conv_w, conv_b, X_bf);
    hipLaunchKernelGGL(gemm_in_kernel, dim3(ROWS / 64, NG / 128), dim3(256), 0, stream,
                       X_bf, wih_bf, b_ih, b_hh, ginT);
    for (int t = 0; t < PP; ++t)
        hipLaunchKernelGGL(lstm_step_kernel, dim3(HH / 16), dim3(256), 0, stream,
                           hs_bf, whh_bf, ginT, c_state, t);
    hipLaunchKernelGGL(tag_kernel, dim3(ROWS / 64), dim3(256), 0, stream,
                       hs_bf, outw_bf, out_b, out);
    hipLaunchKernelGGL(logsoftmax_kernel, dim3((BB * TAGS + 3) / 4), dim3(256), 0, stream,
                       out);
}

// Round 3
// 1828.029 us; speedup vs baseline: 2.2177x; 1.0507x over previous
//
#include <hip/hip_runtime.h>
#include <hip/hip_cooperative_groups.h>
#include <math.h>

namespace cg = cooperative_groups;

#define BB 64
#define PP 80
#define LC 18
#define EE 256
#define HH 1024
#define LCH 4
#define KW 3
#define TAGS 50
#define DD 260          // EE + LCH
#define KPAD 288        // DD padded to multiple of 32
#define ROWS (BB*PP)    // 5120
#define WN (LC-KW+1)    // 16
#define NG (4*HH)       // 4096 gate rows
#define RBLK 128        // persistent blocks
#define RUPB 8          // units per block

typedef __attribute__((ext_vector_type(8))) short short8;   // 8 x bf16
typedef __attribute__((ext_vector_type(4))) short short4v;  // 4 x bf16 (8B store)
typedef __attribute__((ext_vector_type(4))) float floatx4;  // MFMA acc

__device__ __forceinline__ short f2bf(float x) {
    unsigned u = __float_as_uint(x);
    unsigned r = (u + 0x7FFFu + ((u >> 16) & 1u)) >> 16;
    return (short)r;
}
__device__ __forceinline__ float bf2f(short s) {
    return __uint_as_float(((unsigned)(unsigned short)s) << 16);
}
__device__ __forceinline__ float sigf(float x) { return 1.f / (1.f + __expf(-x)); }
__device__ __forceinline__ float wave_reduce_sum(float v) {
    for (int off = 32; off > 0; off >>= 1) v += __shfl_xor(v, off, 64);
    return v;
}

// ---------------- weight prep: fp32 -> bf16 (+padding), zero h_{-1} ----------
__global__ __launch_bounds__(256) void prep_kernel(
    const float* __restrict__ wih, const float* __restrict__ whh,
    const float* __restrict__ outw,
    short* __restrict__ wih_bf, short* __restrict__ whh_bf,
    short* __restrict__ outw_bf, short* __restrict__ hs0)
{
    const int NI = NG * KPAD;
    const int NH = NG * HH;
    const int NO = 64 * HH;
    const int NZ = BB * HH;
    const int total = NI + NH + NO + NZ;
    for (int i = blockIdx.x * 256 + threadIdx.x; i < total; i += gridDim.x * 256) {
        if (i < NI) {
            int r = i / KPAD, c = i - r * KPAD;
            wih_bf[i] = (c < DD) ? f2bf(wih[r * DD + c]) : (short)0;
        } else if (i < NI + NH) {
            int j = i - NI;
            whh_bf[j] = f2bf(whh[j]);
        } else if (i < NI + NH + NO) {
            int k = i - NI - NH;
            int r = k >> 10;
            outw_bf[k] = (r < TAGS) ? f2bf(outw[k]) : (short)0;
        } else {
            hs0[i - NI - NH - NO] = (short)0;
        }
    }
}

// ---------------- embedding + char CNN -> X bf16 [5120][288] ----------------
__global__ __launch_bounds__(256) void embed_kernel(
    const int* __restrict__ sent, const int* __restrict__ chars,
    const float* __restrict__ word_emb, const float* __restrict__ char_emb,
    const float* __restrict__ conv_w, const float* __restrict__ conv_b,
    short* __restrict__ X)
{
    __shared__ float4 ce[LC * 64];
    __shared__ float phi[WN * LCH];
    __shared__ float charrep[LCH];
    const int r = blockIdx.x;
    const int t = threadIdx.x;
    const int lane = t & 63, wv = t >> 6;

    const int cbase = r * LC;
    for (int i = 0; i < 5; ++i) {
        int idx = i * 256 + t;
        if (idx < LC * 64) {
            int j = idx >> 6, e4 = idx & 63;
            int ch = chars[cbase + j];
            ce[idx] = ((const float4*)(char_emb + (size_t)ch * EE))[e4];
        }
    }
    float4 cw[KW][LCH];
    #pragma unroll
    for (int k = 0; k < KW; ++k)
        #pragma unroll
        for (int c = 0; c < LCH; ++c)
            cw[k][c] = ((const float4*)(conv_w + c * (KW * EE) + k * EE))[lane];
    __syncthreads();

    #pragma unroll
    for (int wi = 0; wi < 4; ++wi) {
        int w = wv + wi * 4;
        float acc[LCH] = {0.f, 0.f, 0.f, 0.f};
        #pragma unroll
        for (int k = 0; k < KW; ++k) {
            float4 v = ce[(w + k) * 64 + lane];
            #pragma unroll
            for (int c = 0; c < LCH; ++c)
                acc[c] += v.x * cw[k][c].x + v.y * cw[k][c].y +
                          v.z * cw[k][c].z + v.w * cw[k][c].w;
        }
        #pragma unroll
        for (int c = 0; c < LCH; ++c) {
            float s = wave_reduce_sum(acc[c]);
            if (lane == 0) phi[w * LCH + c] = s;
        }
    }
    __syncthreads();
    if (t < LCH) {
        float m = -1e30f;
        for (int w = 0; w < WN; ++w) m = fmaxf(m, phi[w * LCH + t]);
        charrep[t] = m + conv_b[t];
    }
    __syncthreads();

    const int word = sent[r];
    X[(size_t)r * KPAD + t] = f2bf(word_emb[(size_t)word * EE + t]);
    if (t < LCH) X[(size_t)r * KPAD + EE + t] = f2bf(charrep[t]);
    if (t >= 228) X[(size_t)r * KPAD + 32 + t] = (short)0;
}

// ---------------- input GEMM: ginT[n][r] = X[r]·w_ih[n] + b_ih[n]+b_hh[n] ----
__global__ __launch_bounds__(256) void gemm_in_kernel(
    const short* __restrict__ X, const short* __restrict__ Wih,
    const float* __restrict__ b_ih, const float* __restrict__ b_hh,
    short* __restrict__ ginT)
{
    const int tid = threadIdx.x;
    const int l = tid & 63, wv = tid >> 6;
    const int r0 = blockIdx.x * 64;
    const int n0 = blockIdx.y * 128 + wv * 32;
    const int lr = l & 15, lh = l >> 4;

    floatx4 acc[4][2];
    #pragma unroll
    for (int m = 0; m < 4; ++m)
        #pragma unroll
        for (int n = 0; n < 2; ++n) acc[m][n] = (floatx4)0.f;

    const short* Xb = X + (size_t)(r0 + lr) * KPAD + lh * 8;
    const short* Wb = Wih + (size_t)(n0 + lr) * KPAD + lh * 8;

    #pragma unroll
    for (int k0 = 0; k0 < KPAD; k0 += 32) {
        short8 a0 = *(const short8*)(Xb + k0);
        short8 a1 = *(const short8*)(Xb + 16 * KPAD + k0);
        short8 a2 = *(const short8*)(Xb + 32 * KPAD + k0);
        short8 a3 = *(const short8*)(Xb + 48 * KPAD + k0);
        short8 b0 = *(const short8*)(Wb + k0);
        short8 b1 = *(const short8*)(Wb + 16 * KPAD + k0);
        acc[0][0] = __builtin_amdgcn_mfma_f32_16x16x32_bf16(a0, b0, acc[0][0], 0, 0, 0);
        acc[1][0] = __builtin_amdgcn_mfma_f32_16x16x32_bf16(a1, b0, acc[1][0], 0, 0, 0);
        acc[2][0] = __builtin_amdgcn_mfma_f32_16x16x32_bf16(a2, b0, acc[2][0], 0, 0, 0);
        acc[3][0] = __builtin_amdgcn_mfma_f32_16x16x32_bf16(a3, b0, acc[3][0], 0, 0, 0);
        acc[0][1] = __builtin_amdgcn_mfma_f32_16x16x32_bf16(a0, b1, acc[0][1], 0, 0, 0);
        acc[1][1] = __builtin_amdgcn_mfma_f32_16x16x32_bf16(a1, b1, acc[1][1], 0, 0, 0);
        acc[2][1] = __builtin_amdgcn_mfma_f32_16x16x32_bf16(a2, b1, acc[2][1], 0, 0, 0);
        acc[3][1] = __builtin_amdgcn_mfma_f32_16x16x32_bf16(a3, b1, acc[3][1], 0, 0, 0);
    }
    #pragma unroll
    for (int m = 0; m < 4; ++m)
        #pragma unroll
        for (int n = 0; n < 2; ++n) {
            int col = n0 + n * 16 + lr;
            float bias = b_ih[col] + b_hh[col];
            short4v pack;
            #pragma unroll
            for (int q = 0; q < 4; ++q) pack[q] = f2bf(acc[m][n][q] + bias);
            *(short4v*)(ginT + (size_t)col * ROWS + r0 + m * 16 + lh * 4) = pack;
        }
}

// ---------------- persistent LSTM sequence kernel (cooperative) --------------
// 128 blocks x 256 thr (4 waves). Block owns units u0..u0+7 (all 4 gates ->
// 32 w_hh rows, 2 MFMA N-tiles). Waves split K=1024 into 256-chunks; LDS
// reduce; c-state in registers; grid.sync() between steps.
__global__ __launch_bounds__(256, 1) void lstm_seq_kernel(
    short* __restrict__ hs, const short* __restrict__ Whh,
    const short* __restrict__ ginT)
{
    cg::grid_group grid = cg::this_grid();
    __shared__ float red[4][64][33];

    const int tid = threadIdx.x;
    const int l = tid & 63;
    const int w = tid >> 6;            // wave = K-chunk id
    const int u0 = blockIdx.x * RUPB;
    const int lr = l & 15, lh = l >> 4;

    // B-operand rows: tile0 lane lr -> gate g=lr>>2, unit u0+(lr&3); tile1: +4
    const int g_ = lr >> 2, j_ = lr & 3;
    const short* Bp0 = Whh + (size_t)(g_ * HH + u0 + j_) * HH + w * 256 + lh * 8;
    const short* Bp1 = Bp0 + (size_t)4 * HH;
    const size_t aoff = (size_t)lr * HH + w * 256 + lh * 8;

    // epilogue mapping: thread -> (batch eb, units u0+ej and u0+ej+4)
    const int eb = tid & 63;
    const int ej = tid >> 6;
    const short* ginb = ginT + (size_t)u0 * ROWS + eb;
    float c0 = 0.f, c1 = 0.f;

    for (int t = 0; t < PP; ++t) {
        // issue gin loads early (hide L3 latency under MFMA)
        short gv0[4], gv1[4];
        #pragma unroll
        for (int g = 0; g < 4; ++g) {
            gv0[g] = ginb[(size_t)(g * HH + ej) * ROWS + (size_t)t * 64];
            gv1[g] = ginb[(size_t)(g * HH + ej + 4) * ROWS + (size_t)t * 64];
        }

        const short* A = hs + (size_t)t * BB * HH + aoff;
        floatx4 acc[4][2];
        #pragma unroll
        for (int m = 0; m < 4; ++m) {
            acc[m][0] = (floatx4)0.f;
            acc[m][1] = (floatx4)0.f;
        }
        #pragma unroll
        for (int k0 = 0; k0 < 256; k0 += 32) {
            short8 b0 = *(const short8*)(Bp0 + k0);
            short8 b1 = *(const short8*)(Bp1 + k0);
            short8 a0 = *(const short8*)(A + k0);
            short8 a1 = *(const short8*)(A + 16 * HH + k0);
            short8 a2 = *(const short8*)(A + 32 * HH + k0);
            short8 a3 = *(const short8*)(A + 48 * HH + k0);
            acc[0][0] = __builtin_amdgcn_mfma_f32_16x16x32_bf16(a0, b0, acc[0][0], 0, 0, 0);
            acc[1][0] = __builtin_amdgcn_mfma_f32_16x16x32_bf16(a1, b0, acc[1][0], 0, 0, 0);
            acc[2][0] = __builtin_amdgcn_mfma_f32_16x16x32_bf16(a2, b0, acc[2][0], 0, 0, 0);
            acc[3][0] = __builtin_amdgcn_mfma_f32_16x16x32_bf16(a3, b0, acc[3][0], 0, 0, 0);
            acc[0][1] = __builtin_amdgcn_mfma_f32_16x16x32_bf16(a0, b1, acc[0][1], 0, 0, 0);
            acc[1][1] = __builtin_amdgcn_mfma_f32_16x16x32_bf16(a1, b1, acc[1][1], 0, 0, 0);
            acc[2][1] = __builtin_amdgcn_mfma_f32_16x16x32_bf16(a2, b1, acc[2][1], 0, 0, 0);
            acc[3][1] = __builtin_amdgcn_mfma_f32_16x16x32_bf16(a3, b1, acc[3][1], 0, 0, 0);
        }
        #pragma unroll
        for (int m = 0; m < 4; ++m)
            #pragma unroll
            for (int nt = 0; nt < 2; ++nt)
                #pragma unroll
                for (int q = 0; q < 4; ++q)
                    red[w][m * 16 + lh * 4 + q][nt * 16 + lr] = acc[m][nt][q];
        __syncthreads();

        // reduce 4 K-partials + gates for 2 units
        float s0[4], s1[4];
        #pragma unroll
        for (int g = 0; g < 4; ++g) {
            int n0i = g * 4 + ej;
            int n1i = 16 + g * 4 + ej;
            s0[g] = red[0][eb][n0i] + red[1][eb][n0i] + red[2][eb][n0i] + red[3][eb][n0i]
                    + bf2f(gv0[g]);
            s1[g] = red[0][eb][n1i] + red[1][eb][n1i] + red[2][eb][n1i] + red[3][eb][n1i]
                    + bf2f(gv1[g]);
        }
        {
            float i_ = sigf(s0[0]), f_ = sigf(s0[1]), gg = tanhf(s0[2]), o_ = sigf(s0[3]);
            c0 = f_ * c0 + i_ * gg;
            float hn = o_ * tanhf(c0);
            hs[((size_t)(t + 1) * BB + eb) * HH + u0 + ej] = f2bf(hn);
        }
        {
            float i_ = sigf(s1[0]), f_ = sigf(s1[1]), gg = tanhf(s1[2]), o_ = sigf(s1[3]);
            c1 = f_ * c1 + i_ * gg;
            float hn = o_ * tanhf(c1);
            hs[((size_t)(t + 1) * BB + eb) * HH + u0 + ej + 4] = f2bf(hn);
        }
        grid.sync();
    }
}

// ---------------- tag head: out = hs·out_w^T + out_b (MFMA) ------------------
__global__ __launch_bounds__(256) void tag_kernel(
    const short* __restrict__ hs, const short* __restrict__ outw_bf,
    const float* __restrict__ out_b, float* __restrict__ out)
{
    const int tid = threadIdx.x;
    const int l = tid & 63, wv = tid >> 6;
    const int r0 = blockIdx.x * 64;
    const int n0 = wv * 16;
    const int lr = l & 15, lh = l >> 4;

    const short* A = hs + (size_t)(BB + r0 + lr) * HH + lh * 8;
    const short* Bw = outw_bf + (size_t)(n0 + lr) * HH + lh * 8;

    floatx4 acc[4];
    #pragma unroll
    for (int m = 0; m < 4; ++m) acc[m] = (floatx4)0.f;

    #pragma unroll 4
    for (int k0 = 0; k0 < HH; k0 += 32) {
        short8 b  = *(const short8*)(Bw + k0);
        short8 a0 = *(const short8*)(A + k0);
        short8 a1 = *(const short8*)(A + 16 * HH + k0);
        short8 a2 = *(const short8*)(A + 32 * HH + k0);
        short8 a3 = *(const short8*)(A + 48 * HH + k0);
        acc[0] = __builtin_amdgcn_mfma_f32_16x16x32_bf16(a0, b, acc[0], 0, 0, 0);
        acc[1] = __builtin_amdgcn_mfma_f32_16x16x32_bf16(a1, b, acc[1], 0, 0, 0);
        acc[2] = __builtin_amdgcn_mfma_f32_16x16x32_bf16(a2, b, acc[2], 0, 0, 0);
        acc[3] = __builtin_amdgcn_mfma_f32_16x16x32_bf16(a3, b, acc[3], 0, 0, 0);
    }
    int col = n0 + lr;
    if (col < TAGS) {
        float bias = out_b[col];
        #pragma unroll
        for (int m = 0; m < 4; ++m)
            #pragma unroll
            for (int q = 0; q < 4; ++q) {
                int row = r0 + m * 16 + lh * 4 + q;
                out[(size_t)row * TAGS + col] = acc[m][q] + bias;
            }
    }
}

// ---------------- log_softmax over the P axis, in place ----------------------
__global__ __launch_bounds__(256) void logsoftmax_kernel(float* __restrict__ out)
{
    const int tid = threadIdx.x;
    const int lane = tid & 63;
    const int pair = blockIdx.x * 4 + (tid >> 6);
    if (pair >= BB * TAGS) return;
    const int bb = pair / TAGS, g = pair % TAGS;
    float* base = out + (size_t)bb * PP * TAGS + g;
    float v0 = base[lane * TAGS];
    float v1 = (lane < PP - 64) ? base[(lane + 64) * TAGS] : -1e30f;
    float m = fmaxf(v0, v1);
    for (int off = 32; off > 0; off >>= 1) m = fmaxf(m, __shfl_xor(m, off, 64));
    float s = __expf(v0 - m) + ((lane < PP - 64) ? __expf(v1 - m) : 0.f);
    s = wave_reduce_sum(s);
    float lz = m + __logf(s);
    base[lane * TAGS] = v0 - lz;
    if (lane < PP - 64) base[(lane + 64) * TAGS] = v1 - lz;
}

extern "C" void kernel_launch(void* const* d_in, const int* in_sizes, int n_in,
                              void* d_out, int out_size, void* d_ws, size_t ws_size,
                              hipStream_t stream)
{
    const int*   sent     = (const int*)d_in[0];
    const int*   chars    = (const int*)d_in[1];
    const float* word_emb = (const float*)d_in[2];
    const float* char_emb = (const float*)d_in[3];
    const float* conv_w   = (const float*)d_in[4];
    const float* conv_b   = (const float*)d_in[5];
    const float* w_ih     = (const float*)d_in[6];
    const float* w_hh     = (const float*)d_in[7];
    const float* b_ih     = (const float*)d_in[8];
    const float* b_hh     = (const float*)d_in[9];
    const float* out_w    = (const float*)d_in[10];
    const float* out_b    = (const float*)d_in[11];
    float* out = (float*)d_out;

    short* X_bf    = (short*)d_ws;                             // 5120*288
    short* wih_bf  = X_bf + (size_t)ROWS * KPAD;               // 4096*288
    short* whh_bf  = wih_bf + (size_t)NG * KPAD;               // 4096*1024
    short* outw_bf = whh_bf + (size_t)NG * HH;                 // 64*1024
    short* ginT    = outw_bf + (size_t)64 * HH;                // 4096*5120
    short* hs_bf   = ginT + (size_t)NG * ROWS;                 // 81*64*1024

    hipLaunchKernelGGL(prep_kernel, dim3(2048), dim3(256), 0, stream,
                       w_ih, w_hh, out_w, wih_bf, whh_bf, outw_bf, hs_bf);
    hipLaunchKernelGGL(embed_kernel, dim3(ROWS), dim3(256), 0, stream,
                       sent, chars, word_emb, char_emb, conv_w, conv_b, X_bf);
    hipLaunchKernelGGL(gemm_in_kernel, dim3(ROWS / 64, NG / 128), dim3(256), 0, stream,
                       X_bf, wih_bf, b_ih, b_hh, ginT);
    {
        void* kargs[3] = { (void*)&hs_bf, (void*)&whh_bf, (void*)&ginT };
        hipLaunchCooperativeKernel((void*)lstm_seq_kernel, dim3(RBLK), dim3(256),
                                   kargs, 0, stream);
    }
    hipLaunchKernelGGL(tag_kernel, dim3(ROWS / 64), dim3(256), 0, stream,
                       hs_bf, outw_bf, out_b, out);
    hipLaunchKernelGGL(logsoftmax_kernel, dim3((BB * TAGS + 3) / 4), dim3(256), 0, stream,
                       out);
}

// Round 4
// 1801.878 us; speedup vs baseline: 2.2498x; 1.0145x over previous
//
#include <hip/hip_runtime.h>
#include <math.h>

#define BB 64
#define PP 80
#define LC 18
#define EE 256
#define HH 1024
#define LCH 4
#define KW 3
#define TAGS 50
#define DD 260          // EE + LCH
#define KPAD 288        // DD padded to multiple of 32
#define ROWS (BB*PP)    // 5120
#define WN (LC-KW+1)    // 16
#define NG (4*HH)       // 4096 gate rows
#define NBLK 64         // persistent blocks (one per 16 hidden units)
#define HSTEP (128*64*8) // shorts per timestep of hst: [128 ublk][64 b][8 u]

typedef __attribute__((ext_vector_type(8))) short short8;   // 8 x bf16
typedef __attribute__((ext_vector_type(4))) short short4v;  // 4 x bf16 (8B store)
typedef __attribute__((ext_vector_type(4))) float floatx4;  // MFMA acc

__device__ __forceinline__ short f2bf(float x) {
    unsigned u = __float_as_uint(x);
    unsigned r = (u + 0x7FFFu + ((u >> 16) & 1u)) >> 16;
    return (short)r;
}
__device__ __forceinline__ float bf2f(short s) {
    return __uint_as_float(((unsigned)(unsigned short)s) << 16);
}
__device__ __forceinline__ float sigf(float x) { return 1.f / (1.f + __expf(-x)); }
__device__ __forceinline__ float tanhfast(float x) {
    float e = __expf(2.f * x);
    return 1.f - 2.f / (e + 1.f);
}
__device__ __forceinline__ float wave_reduce_sum(float v) {
    for (int off = 32; off > 0; off >>= 1) v += __shfl_xor(v, off, 64);
    return v;
}

// device-scope sense-reversing barrier: bar[0]=count, bar[64]=generation
__device__ __forceinline__ void grid_barrier(unsigned* bar) {
    __syncthreads();
    if (threadIdx.x == 0) {
        __threadfence();   // flush this XCD's dirty lines to coherence point
        unsigned g = __hip_atomic_load(bar + 64, __ATOMIC_RELAXED, __HIP_MEMORY_SCOPE_AGENT);
        unsigned a = __hip_atomic_fetch_add(bar, 1u, __ATOMIC_ACQ_REL, __HIP_MEMORY_SCOPE_AGENT);
        if (a == NBLK - 1) {
            __hip_atomic_store(bar, 0u, __ATOMIC_RELAXED, __HIP_MEMORY_SCOPE_AGENT);
            __hip_atomic_store(bar + 64, g + 1u, __ATOMIC_RELEASE, __HIP_MEMORY_SCOPE_AGENT);
        } else {
            while (__hip_atomic_load(bar + 64, __ATOMIC_ACQUIRE, __HIP_MEMORY_SCOPE_AGENT) == g)
                __builtin_amdgcn_s_sleep(1);
        }
        __threadfence();   // invalidate L1/L2 so remote h-writes are visible
    }
    __syncthreads();
}

// ---- prep: wih pad->bf16, whh -> fragment-major pack, outw pad, bar zero ----
__global__ __launch_bounds__(256) void prep_kernel(
    const float* __restrict__ wih, const float* __restrict__ whh,
    const float* __restrict__ outw,
    short* __restrict__ wih_bf, short* __restrict__ wpk,
    short* __restrict__ outw_bf, unsigned* __restrict__ bar)
{
    if (blockIdx.x == 0 && threadIdx.x == 0) { bar[0] = 0u; bar[64] = 0u; }
    const int NI = NG * KPAD;       // 1179648
    const int NH = NG * HH;         // 4194304
    const int NO = 64 * HH;         // 65536
    const int total = NI + NH + NO;
    for (int i = blockIdx.x * 256 + threadIdx.x; i < total; i += gridDim.x * 256) {
        if (i < NI) {
            int r = i / KPAD, c = i - r * KPAD;
            wih_bf[i] = (c < DD) ? f2bf(wih[r * DD + c]) : (short)0;
        } else if (i < NI + NH) {
            int o = i - NI;
            // wpk[bl][w][kk][lane][e] <- whh[w*1024 + bl*16 + (lane&15)][kk*32+(lane>>4)*8+e]
            int e  = o & 7;
            int l  = (o >> 3) & 63;
            int kk = (o >> 9) & 31;
            int w  = (o >> 14) & 3;
            int bl = o >> 16;
            int row = w * HH + bl * 16 + (l & 15);
            int col = kk * 32 + (l >> 4) * 8 + e;
            wpk[o] = f2bf(whh[(size_t)row * HH + col]);
        } else {
            int k = i - NI - NH;
            int r = k >> 10;
            outw_bf[k] = (r < TAGS) ? f2bf(outw[k]) : (short)0;
        }
    }
}

// ---------------- embedding + char CNN -> X bf16 [5120][288] ----------------
__global__ __launch_bounds__(256) void embed_kernel(
    const int* __restrict__ sent, const int* __restrict__ chars,
    const float* __restrict__ word_emb, const float* __restrict__ char_emb,
    const float* __restrict__ conv_w, const float* __restrict__ conv_b,
    short* __restrict__ X)
{
    __shared__ float4 ce[LC * 64];
    __shared__ float phi[WN * LCH];
    __shared__ float charrep[LCH];
    const int r = blockIdx.x;
    const int t = threadIdx.x;
    const int lane = t & 63, wv = t >> 6;

    const int cbase = r * LC;
    for (int i = 0; i < 5; ++i) {
        int idx = i * 256 + t;
        if (idx < LC * 64) {
            int j = idx >> 6, e4 = idx & 63;
            int ch = chars[cbase + j];
            ce[idx] = ((const float4*)(char_emb + (size_t)ch * EE))[e4];
        }
    }
    float4 cw[KW][LCH];
    #pragma unroll
    for (int k = 0; k < KW; ++k)
        #pragma unroll
        for (int c = 0; c < LCH; ++c)
            cw[k][c] = ((const float4*)(conv_w + c * (KW * EE) + k * EE))[lane];
    __syncthreads();

    #pragma unroll
    for (int wi = 0; wi < 4; ++wi) {
        int w = wv + wi * 4;
        float acc[LCH] = {0.f, 0.f, 0.f, 0.f};
        #pragma unroll
        for (int k = 0; k < KW; ++k) {
            float4 v = ce[(w + k) * 64 + lane];
            #pragma unroll
            for (int c = 0; c < LCH; ++c)
                acc[c] += v.x * cw[k][c].x + v.y * cw[k][c].y +
                          v.z * cw[k][c].z + v.w * cw[k][c].w;
        }
        #pragma unroll
        for (int c = 0; c < LCH; ++c) {
            float s = wave_reduce_sum(acc[c]);
            if (lane == 0) phi[w * LCH + c] = s;
        }
    }
    __syncthreads();
    if (t < LCH) {
        float m = -1e30f;
        for (int w = 0; w < WN; ++w) m = fmaxf(m, phi[w * LCH + t]);
        charrep[t] = m + conv_b[t];
    }
    __syncthreads();

    const int word = sent[r];
    X[(size_t)r * KPAD + t] = f2bf(word_emb[(size_t)word * EE + t]);
    if (t < LCH) X[(size_t)r * KPAD + EE + t] = f2bf(charrep[t]);
    if (t >= 228) X[(size_t)r * KPAD + 32 + t] = (short)0;
}

// ---------------- input GEMM: ginT[n][r] = X[r]·w_ih[n] + b_ih[n]+b_hh[n] ----
__global__ __launch_bounds__(256) void gemm_in_kernel(
    const short* __restrict__ X, const short* __restrict__ Wih,
    const float* __restrict__ b_ih, const float* __restrict__ b_hh,
    short* __restrict__ ginT)
{
    const int tid = threadIdx.x;
    const int l = tid & 63, wv = tid >> 6;
    const int r0 = blockIdx.x * 64;
    const int n0 = blockIdx.y * 128 + wv * 32;
    const int lr = l & 15, lh = l >> 4;

    floatx4 acc[4][2];
    #pragma unroll
    for (int m = 0; m < 4; ++m)
        #pragma unroll
        for (int n = 0; n < 2; ++n) acc[m][n] = (floatx4)0.f;

    const short* Xb = X + (size_t)(r0 + lr) * KPAD + lh * 8;
    const short* Wb = Wih + (size_t)(n0 + lr) * KPAD + lh * 8;

    #pragma unroll
    for (int k0 = 0; k0 < KPAD; k0 += 32) {
        short8 a0 = *(const short8*)(Xb + k0);
        short8 a1 = *(const short8*)(Xb + 16 * KPAD + k0);
        short8 a2 = *(const short8*)(Xb + 32 * KPAD + k0);
        short8 a3 = *(const short8*)(Xb + 48 * KPAD + k0);
        short8 b0 = *(const short8*)(Wb + k0);
        short8 b1 = *(const short8*)(Wb + 16 * KPAD + k0);
        acc[0][0] = __builtin_amdgcn_mfma_f32_16x16x32_bf16(a0, b0, acc[0][0], 0, 0, 0);
        acc[1][0] = __builtin_amdgcn_mfma_f32_16x16x32_bf16(a1, b0, acc[1][0], 0, 0, 0);
        acc[2][0] = __builtin_amdgcn_mfma_f32_16x16x32_bf16(a2, b0, acc[2][0], 0, 0, 0);
        acc[3][0] = __builtin_amdgcn_mfma_f32_16x16x32_bf16(a3, b0, acc[3][0], 0, 0, 0);
        acc[0][1] = __builtin_amdgcn_mfma_f32_16x16x32_bf16(a0, b1, acc[0][1], 0, 0, 0);
        acc[1][1] = __builtin_amdgcn_mfma_f32_16x16x32_bf16(a1, b1, acc[1][1], 0, 0, 0);
        acc[2][1] = __builtin_amdgcn_mfma_f32_16x16x32_bf16(a2, b1, acc[2][1], 0, 0, 0);
        acc[3][1] = __builtin_amdgcn_mfma_f32_16x16x32_bf16(a3, b1, acc[3][1], 0, 0, 0);
    }
    #pragma unroll
    for (int m = 0; m < 4; ++m)
        #pragma unroll
        for (int n = 0; n < 2; ++n) {
            int col = n0 + n * 16 + lr;
            float bias = b_ih[col] + b_hh[col];
            short4v pack;
            #pragma unroll
            for (int q = 0; q < 4; ++q) pack[q] = f2bf(acc[m][n][q] + bias);
            *(short4v*)(ginT + (size_t)col * ROWS + r0 + m * 16 + lh * 4) = pack;
        }
}

// ---------------- persistent LSTM: weights in registers, custom barrier ------
// 64 blocks x 256 thr. Block bl: units u0=bl*16..+15. Wave w = gate w,
// B-rows = whh[w*HH + u0 .. +15] held in 32x short8 registers for all steps.
// hst layout per t: [128 ublk][64 b][8 u] bf16 (fully coalesced R/W).
__global__ __launch_bounds__(256, 1) void lstm_seq_kernel(
    short* __restrict__ hst, const short* __restrict__ wpk,
    const short* __restrict__ ginT, unsigned* __restrict__ bar)
{
    __shared__ float lds_g[4][64][18];
    __shared__ short hbuf[64][24];

    const int tid = threadIdx.x;
    const int l = tid & 63;
    const int w = tid >> 6;
    const int bl = blockIdx.x;
    const int u0 = bl * 16;
    const int lr = l & 15, lh = l >> 4;

    // load this wave's recurrent weights into registers (resident for 80 steps)
    short8 barr[32];
    const short* wb = wpk + ((size_t)(bl * 4 + w) * 32) * 512 + l * 8;
    #pragma unroll
    for (int kk = 0; kk < 32; ++kk)
        barr[kk] = *(const short8*)(wb + kk * 512);

    const int eb = l;       // epilogue: batch = lane
    const int grp = w;      // epilogue: unit group (4 units)
    float c[4] = {0.f, 0.f, 0.f, 0.f};

    // gin for t=0
    float gv[4][4];
    #pragma unroll
    for (int g = 0; g < 4; ++g)
        #pragma unroll
        for (int j = 0; j < 4; ++j)
            gv[g][j] = bf2f(ginT[(size_t)(g * HH + u0 + grp * 4 + j) * ROWS + eb]);

    for (int t = 0; t < PP; ++t) {
        if (t > 0) {
            const short* A = hst + (size_t)(t - 1) * HSTEP;
            floatx4 acc[4];
            #pragma unroll
            for (int m = 0; m < 4; ++m) acc[m] = (floatx4)0.f;
            #pragma unroll
            for (int kk = 0; kk < 32; ++kk) {
                #pragma unroll
                for (int m = 0; m < 4; ++m) {
                    short8 a = *(const short8*)(A + ((kk * 4 + lh) * 64 + m * 16 + lr) * 8);
                    acc[m] = __builtin_amdgcn_mfma_f32_16x16x32_bf16(a, barr[kk], acc[m], 0, 0, 0);
                }
            }
            #pragma unroll
            for (int m = 0; m < 4; ++m)
                #pragma unroll
                for (int q = 0; q < 4; ++q)
                    lds_g[w][m * 16 + lh * 4 + q][lr] = acc[m][q];
            __syncthreads();
        }

        // fused gate epilogue: this thread owns (batch eb, units u0+grp*4..+3)
        #pragma unroll
        for (int j = 0; j < 4; ++j) {
            int uu = grp * 4 + j;
            float si = gv[0][j], sf = gv[1][j], sg = gv[2][j], so = gv[3][j];
            if (t > 0) {
                si += lds_g[0][eb][uu];
                sf += lds_g[1][eb][uu];
                sg += lds_g[2][eb][uu];
                so += lds_g[3][eb][uu];
            }
            si = sigf(si); sf = sigf(sf); sg = tanhfast(sg); so = sigf(so);
            c[j] = sf * c[j] + si * sg;
            hbuf[eb][uu] = f2bf(so * tanhfast(c[j]));
        }

        // prefetch gin for t+1 (overlaps barrier spin)
        if (t + 1 < PP) {
            #pragma unroll
            for (int g = 0; g < 4; ++g)
                #pragma unroll
                for (int j = 0; j < 4; ++j)
                    gv[g][j] = bf2f(ginT[(size_t)(g * HH + u0 + grp * 4 + j) * ROWS
                                         + (t + 1) * 64 + eb]);
        }
        __syncthreads();

        // coalesced h store: 2 waves x 1KB contiguous
        if (tid < 128) {
            int ub = tid >> 6, row = tid & 63;
            *(short8*)(hst + (size_t)t * HSTEP + ((size_t)(bl * 2 + ub) * 64 + row) * 8)
                = *(const short8*)(&hbuf[row][ub * 8]);
        }

        if (t + 1 < PP) grid_barrier(bar);
    }
}

// ---------------- tag head: out = hs·out_w^T + out_b (MFMA) ------------------
// 80 blocks x 4 waves; block = timestep t (64 flat rows), wave wv = 16 tags
__global__ __launch_bounds__(256) void tag_kernel(
    const short* __restrict__ hst, const short* __restrict__ outw_bf,
    const float* __restrict__ out_b, float* __restrict__ out)
{
    const int tid = threadIdx.x;
    const int l = tid & 63, wv = tid >> 6;
    const int t = blockIdx.x;
    const int n0 = wv * 16;
    const int lr = l & 15, lh = l >> 4;

    const short* At = hst + (size_t)t * HSTEP;
    const short* Bw = outw_bf + (size_t)(n0 + lr) * HH + lh * 8;

    floatx4 acc[4];
    #pragma unroll
    for (int m = 0; m < 4; ++m) acc[m] = (floatx4)0.f;

    #pragma unroll 4
    for (int kk = 0; kk < 32; ++kk) {
        short8 b = *(const short8*)(Bw + kk * 32);
        #pragma unroll
        for (int m = 0; m < 4; ++m) {
            short8 a = *(const short8*)(At + ((kk * 4 + lh) * 64 + m * 16 + lr) * 8);
            acc[m] = __builtin_amdgcn_mfma_f32_16x16x32_bf16(a, b, acc[m], 0, 0, 0);
        }
    }
    int col = n0 + lr;
    if (col < TAGS) {
        float bias = out_b[col];
        #pragma unroll
        for (int m = 0; m < 4; ++m)
            #pragma unroll
            for (int q = 0; q < 4; ++q) {
                int row = t * 64 + m * 16 + lh * 4 + q;
                out[(size_t)row * TAGS + col] = acc[m][q] + bias;
            }
    }
}

// ---------------- log_softmax over the P axis, in place ----------------------
__global__ __launch_bounds__(256) void logsoftmax_kernel(float* __restrict__ out)
{
    const int tid = threadIdx.x;
    const int lane = tid & 63;
    const int pair = blockIdx.x * 4 + (tid >> 6);
    if (pair >= BB * TAGS) return;
    const int bb = pair / TAGS, g = pair % TAGS;
    float* base = out + (size_t)bb * PP * TAGS + g;
    float v0 = base[lane * TAGS];
    float v1 = (lane < PP - 64) ? base[(lane + 64) * TAGS] : -1e30f;
    float m = fmaxf(v0, v1);
    for (int off = 32; off > 0; off >>= 1) m = fmaxf(m, __shfl_xor(m, off, 64));
    float s = __expf(v0 - m) + ((lane < PP - 64) ? __expf(v1 - m) : 0.f);
    s = wave_reduce_sum(s);
    float lz = m + __logf(s);
    base[lane * TAGS] = v0 - lz;
    if (lane < PP - 64) base[(lane + 64) * TAGS] = v1 - lz;
}

extern "C" void kernel_launch(void* const* d_in, const int* in_sizes, int n_in,
                              void* d_out, int out_size, void* d_ws, size_t ws_size,
                              hipStream_t stream)
{
    const int*   sent     = (const int*)d_in[0];
    const int*   chars    = (const int*)d_in[1];
    const float* word_emb = (const float*)d_in[2];
    const float* char_emb = (const float*)d_in[3];
    const float* conv_w   = (const float*)d_in[4];
    const float* conv_b   = (const float*)d_in[5];
    const float* w_ih     = (const float*)d_in[6];
    const float* w_hh     = (const float*)d_in[7];
    const float* b_ih     = (const float*)d_in[8];
    const float* b_hh     = (const float*)d_in[9];
    const float* out_w    = (const float*)d_in[10];
    const float* out_b    = (const float*)d_in[11];
    float* out = (float*)d_out;

    short* X_bf    = (short*)d_ws;                             // 5120*288
    short* wih_bf  = X_bf + (size_t)ROWS * KPAD;               // 4096*288
    short* wpk     = wih_bf + (size_t)NG * KPAD;               // 4096*1024 (frag-major)
    short* outw_bf = wpk + (size_t)NG * HH;                    // 64*1024
    short* ginT    = outw_bf + (size_t)64 * HH;                // 4096*5120
    short* hst     = ginT + (size_t)NG * ROWS;                 // 80*HSTEP
    unsigned* bar  = (unsigned*)(hst + (size_t)PP * HSTEP);    // 128 words

    hipLaunchKernelGGL(prep_kernel, dim3(2048), dim3(256), 0, stream,
                       w_ih, w_hh, out_w, wih_bf, wpk, outw_bf, bar);
    hipLaunchKernelGGL(embed_kernel, dim3(ROWS), dim3(256), 0, stream,
                       sent, chars, word_emb, char_emb, conv_w, conv_b, X_bf);
    hipLaunchKernelGGL(gemm_in_kernel, dim3(ROWS / 64, NG / 128), dim3(256), 0, stream,
                       X_bf, wih_bf, b_ih, b_hh, ginT);
    {
        void* kargs[4] = { (void*)&hst, (void*)&wpk, (void*)&ginT, (void*)&bar };
        hipLaunchCooperativeKernel((void*)lstm_seq_kernel, dim3(NBLK), dim3(256),
                                   kargs, 0, stream);
    }
    hipLaunchKernelGGL(tag_kernel, dim3(PP), dim3(256), 0, stream,
                       hst, outw_bf, out_b, out);
    hipLaunchKernelGGL(logsoftmax_kernel, dim3((BB * TAGS + 3) / 4), dim3(256), 0, stream,
                       out);
}

// Round 5
// 1602.749 us; speedup vs baseline: 2.5294x; 1.1242x over previous
//
#include <hip/hip_runtime.h>
#include <math.h>

#define BB 64
#define PP 80
#define LC 18
#define EE 256
#define HH 1024
#define LCH 4
#define KW 3
#define TAGS 50
#define DD 260          // EE + LCH
#define KPAD 288        // DD padded to multiple of 32
#define ROWS (BB*PP)    // 5120
#define WN (LC-KW+1)    // 16
#define NG (4*HH)       // 4096 gate rows
#define GRP 4           // batch groups (16 batches each)
#define NBLK (GRP*64)   // 256 persistent blocks
#define HSTEP (GRP*32*512) // shorts per timestep of hst: [4 g][32 kk][64 lane][8 e]

typedef __attribute__((ext_vector_type(8))) short short8;   // 8 x bf16
typedef __attribute__((ext_vector_type(4))) short short4v;  // 4 x bf16 (8B store)
typedef __attribute__((ext_vector_type(4))) float floatx4;  // MFMA acc

__device__ __forceinline__ short f2bf(float x) {
    unsigned u = __float_as_uint(x);
    unsigned r = (u + 0x7FFFu + ((u >> 16) & 1u)) >> 16;
    return (short)r;
}
__device__ __forceinline__ float bf2f(short s) {
    return __uint_as_float(((unsigned)(unsigned short)s) << 16);
}
__device__ __forceinline__ float sigf(float x) { return 1.f / (1.f + __expf(-x)); }
__device__ __forceinline__ float tanhfast(float x) {
    float e = __expf(2.f * x);
    return 1.f - 2.f / (e + 1.f);
}
__device__ __forceinline__ float wave_reduce_sum(float v) {
    for (int off = 32; off > 0; off >>= 1) v += __shfl_xor(v, off, 64);
    return v;
}

// ---- prep: wih pad->bf16, whh -> fragment-major pack, outw pad, flags zero --
__global__ __launch_bounds__(256) void prep_kernel(
    const float* __restrict__ wih, const float* __restrict__ whh,
    const float* __restrict__ outw,
    short* __restrict__ wih_bf, short* __restrict__ wpk,
    short* __restrict__ outw_bf, unsigned* __restrict__ flags)
{
    const int NI = NG * KPAD;       // 1179648
    const int NH = NG * HH;         // 4194304
    const int NO = 64 * HH;         // 65536
    const int total = NI + NH + NO;
    for (int i = blockIdx.x * 256 + threadIdx.x; i < total; i += gridDim.x * 256) {
        if (i < NI) {
            int r = i / KPAD, c = i - r * KPAD;
            wih_bf[i] = (c < DD) ? f2bf(wih[r * DD + c]) : (short)0;
        } else if (i < NI + NH) {
            int o = i - NI;
            // wpk[bl][w][kk][lane][e] <- whh[w*1024 + bl*16 + (l&15)][kk*32+(l>>4)*8+e]
            int e  = o & 7;
            int l  = (o >> 3) & 63;
            int kk = (o >> 9) & 31;
            int w  = (o >> 14) & 3;
            int bl = o >> 16;
            int row = w * HH + bl * 16 + (l & 15);
            int col = kk * 32 + (l >> 4) * 8 + e;
            wpk[o] = f2bf(whh[(size_t)row * HH + col]);
        } else {
            int k = i - NI - NH;
            int r = k >> 10;
            outw_bf[k] = (r < TAGS) ? f2bf(outw[k]) : (short)0;
        }
    }
    // zero sync flags (timestep-indexed; must be re-zeroed every launch)
    for (int i = blockIdx.x * 256 + threadIdx.x; i < PP * GRP * 64; i += gridDim.x * 256)
        flags[i] = 0u;
}

// ---------------- embedding + char CNN -> X bf16 [5120][288] ----------------
__global__ __launch_bounds__(256) void embed_kernel(
    const int* __restrict__ sent, const int* __restrict__ chars,
    const float* __restrict__ word_emb, const float* __restrict__ char_emb,
    const float* __restrict__ conv_w, const float* __restrict__ conv_b,
    short* __restrict__ X)
{
    __shared__ float4 ce[LC * 64];
    __shared__ float phi[WN * LCH];
    __shared__ float charrep[LCH];
    const int r = blockIdx.x;
    const int t = threadIdx.x;
    const int lane = t & 63, wv = t >> 6;

    const int cbase = r * LC;
    for (int i = 0; i < 5; ++i) {
        int idx = i * 256 + t;
        if (idx < LC * 64) {
            int j = idx >> 6, e4 = idx & 63;
            int ch = chars[cbase + j];
            ce[idx] = ((const float4*)(char_emb + (size_t)ch * EE))[e4];
        }
    }
    float4 cw[KW][LCH];
    #pragma unroll
    for (int k = 0; k < KW; ++k)
        #pragma unroll
        for (int c = 0; c < LCH; ++c)
            cw[k][c] = ((const float4*)(conv_w + c * (KW * EE) + k * EE))[lane];
    __syncthreads();

    #pragma unroll
    for (int wi = 0; wi < 4; ++wi) {
        int w = wv + wi * 4;
        float acc[LCH] = {0.f, 0.f, 0.f, 0.f};
        #pragma unroll
        for (int k = 0; k < KW; ++k) {
            float4 v = ce[(w + k) * 64 + lane];
            #pragma unroll
            for (int c = 0; c < LCH; ++c)
                acc[c] += v.x * cw[k][c].x + v.y * cw[k][c].y +
                          v.z * cw[k][c].z + v.w * cw[k][c].w;
        }
        #pragma unroll
        for (int c = 0; c < LCH; ++c) {
            float s = wave_reduce_sum(acc[c]);
            if (lane == 0) phi[w * LCH + c] = s;
        }
    }
    __syncthreads();
    if (t < LCH) {
        float m = -1e30f;
        for (int w = 0; w < WN; ++w) m = fmaxf(m, phi[w * LCH + t]);
        charrep[t] = m + conv_b[t];
    }
    __syncthreads();

    const int word = sent[r];
    X[(size_t)r * KPAD + t] = f2bf(word_emb[(size_t)word * EE + t]);
    if (t < LCH) X[(size_t)r * KPAD + EE + t] = f2bf(charrep[t]);
    if (t >= 228) X[(size_t)r * KPAD + 32 + t] = (short)0;
}

// ---- input GEMM -> ginP[t][g][bl][gate][uu][b16] (coalesced per-step read) --
__global__ __launch_bounds__(256) void gemm_in_kernel(
    const short* __restrict__ X, const short* __restrict__ Wih,
    const float* __restrict__ b_ih, const float* __restrict__ b_hh,
    short* __restrict__ ginP)
{
    const int tid = threadIdx.x;
    const int l = tid & 63, wv = tid >> 6;
    const int r0 = blockIdx.x * 64;          // rows = t*64 + b
    const int n0 = blockIdx.y * 128 + wv * 32;
    const int lr = l & 15, lh = l >> 4;

    floatx4 acc[4][2];
    #pragma unroll
    for (int m = 0; m < 4; ++m)
        #pragma unroll
        for (int n = 0; n < 2; ++n) acc[m][n] = (floatx4)0.f;

    const short* Xb = X + (size_t)(r0 + lr) * KPAD + lh * 8;
    const short* Wb = Wih + (size_t)(n0 + lr) * KPAD + lh * 8;

    #pragma unroll
    for (int k0 = 0; k0 < KPAD; k0 += 32) {
        short8 a0 = *(const short8*)(Xb + k0);
        short8 a1 = *(const short8*)(Xb + 16 * KPAD + k0);
        short8 a2 = *(const short8*)(Xb + 32 * KPAD + k0);
        short8 a3 = *(const short8*)(Xb + 48 * KPAD + k0);
        short8 b0 = *(const short8*)(Wb + k0);
        short8 b1 = *(const short8*)(Wb + 16 * KPAD + k0);
        acc[0][0] = __builtin_amdgcn_mfma_f32_16x16x32_bf16(a0, b0, acc[0][0], 0, 0, 0);
        acc[1][0] = __builtin_amdgcn_mfma_f32_16x16x32_bf16(a1, b0, acc[1][0], 0, 0, 0);
        acc[2][0] = __builtin_amdgcn_mfma_f32_16x16x32_bf16(a2, b0, acc[2][0], 0, 0, 0);
        acc[3][0] = __builtin_amdgcn_mfma_f32_16x16x32_bf16(a3, b0, acc[3][0], 0, 0, 0);
        acc[0][1] = __builtin_amdgcn_mfma_f32_16x16x32_bf16(a0, b1, acc[0][1], 0, 0, 0);
        acc[1][1] = __builtin_amdgcn_mfma_f32_16x16x32_bf16(a1, b1, acc[1][1], 0, 0, 0);
        acc[2][1] = __builtin_amdgcn_mfma_f32_16x16x32_bf16(a2, b1, acc[2][1], 0, 0, 0);
        acc[3][1] = __builtin_amdgcn_mfma_f32_16x16x32_bf16(a3, b1, acc[3][1], 0, 0, 0);
    }
    // rows r0+m*16+lh*4+q: t=blockIdx.x, g=m, b16=lh*4+q
    #pragma unroll
    for (int m = 0; m < 4; ++m)
        #pragma unroll
        for (int n = 0; n < 2; ++n) {
            int col = n0 + n * 16 + lr;            // gate-unit index 0..4095
            float bias = b_ih[col] + b_hh[col];
            short4v pack;
            #pragma unroll
            for (int q = 0; q < 4; ++q) pack[q] = f2bf(acc[m][n][q] + bias);
            int w_ = col >> 10, bl_ = (col >> 4) & 63, uu_ = col & 15;
            size_t addr = ((((size_t)(blockIdx.x * GRP + m) * 64 + bl_) * 4 + w_) * 16
                           + uu_) * 16 + lh * 4;
            *(short4v*)(ginP + addr) = pack;
        }
}

// ---------------- persistent LSTM: flag-sync, batch-split groups -------------
// 256 blocks x 256 thr. Block = (g = bid>>6 batch group, bl = bid&63 unit blk).
// Wave w = gate w; 16 units x K=1024 weights resident in registers.
// hst[t] layout: [4 g][32 kk][64 lane][8 e] bf16.
__global__ __launch_bounds__(256, 1) void lstm_seq_kernel(
    short* __restrict__ hst, const short* __restrict__ wpk,
    const short* __restrict__ ginP, unsigned* __restrict__ flags)
{
    __shared__ float lds_g[4][16][20];
    __shared__ short hbuf[16][18];

    const int tid = threadIdx.x;
    const int l = tid & 63;
    const int w = tid >> 6;             // wave = gate
    const int g  = blockIdx.x >> 6;     // batch group (16 batches)
    const int bl = blockIdx.x & 63;     // unit block (16 units)

    // resident recurrent weights: 32x short8 (same pack as before)
    short8 barr[32];
    const short* wb = wpk + ((size_t)(bl * 4 + w) * 32) * 512 + l * 8;
    #pragma unroll
    for (int kk = 0; kk < 32; ++kk)
        barr[kk] = *(const short8*)(wb + kk * 512);

    const int b16 = tid & 15;           // epilogue: batch within group
    const int uu  = tid >> 4;           // epilogue: unit 0..15
    float c = 0.f;

    // gin for t=0
    float gv[4];
    {
        const short* gb = ginP + (((size_t)g * 64 + bl) * 4) * 256 + uu * 16 + b16;
        #pragma unroll
        for (int q = 0; q < 4; ++q) gv[q] = bf2f(gb[q * 256]);
    }

    for (int t = 0; t < PP; ++t) {
        if (t > 0) {
            // wait for all 64 producer blocks of this group, one flag per lane
            if (tid < 64) {
                const unsigned* fl = flags + ((size_t)(t - 1) * GRP + g) * 64;
                while (__hip_atomic_load(fl + tid, __ATOMIC_RELAXED,
                                         __HIP_MEMORY_SCOPE_AGENT) == 0u)
                    __builtin_amdgcn_s_sleep(1);
            }
            __syncthreads();
            __builtin_amdgcn_fence(__ATOMIC_ACQUIRE, "agent");

            const short* A = hst + (size_t)(t - 1) * HSTEP + g * 16384;
            floatx4 acc = (floatx4)0.f;
            #pragma unroll
            for (int kk = 0; kk < 32; ++kk) {
                short8 a = *(const short8*)(A + kk * 512 + l * 8);
                acc = __builtin_amdgcn_mfma_f32_16x16x32_bf16(a, barr[kk], acc, 0, 0, 0);
            }
            #pragma unroll
            for (int q = 0; q < 4; ++q)
                lds_g[w][(l >> 4) * 4 + q][l & 15] = acc[q];
            __syncthreads();
        }

        // fused gate epilogue: thread owns (batch b16, unit u0+uu)
        float s0 = gv[0], s1 = gv[1], s2 = gv[2], s3 = gv[3];
        if (t > 0) {
            s0 += lds_g[0][b16][uu];
            s1 += lds_g[1][b16][uu];
            s2 += lds_g[2][b16][uu];
            s3 += lds_g[3][b16][uu];
        }
        float i_ = sigf(s0), f_ = sigf(s1), g_ = tanhfast(s2), o_ = sigf(s3);
        c = f_ * c + i_ * g_;
        hbuf[b16][uu] = f2bf(o_ * tanhfast(c));

        // prefetch gin for t+1 (hidden under store/fence/poll)
        if (t + 1 < PP) {
            const short* gb = ginP + (((size_t)(t + 1) * GRP + g) * 64 + bl) * 1024
                              + uu * 16 + b16;
            #pragma unroll
            for (int q = 0; q < 4; ++q) gv[q] = bf2f(gb[q * 256]);
        }
        __syncthreads();

        // coalesced h store (wave 0 only): two 256B segments
        if (tid < 32) {
            int lh = tid >> 4, bb = tid & 15;
            short8 hv = *(const short8*)(&hbuf[bb][lh * 8]);
            int lt = ((2 * bl + lh) & 3) * 16 + bb;
            *(short8*)(hst + (size_t)t * HSTEP + g * 16384 + (bl >> 1) * 512 + lt * 8) = hv;
        }
        if (t + 1 < PP && w == 0) {
            __builtin_amdgcn_fence(__ATOMIC_RELEASE, "agent");  // L2 -> IF writeback
            if (tid == 0)
                __hip_atomic_store(flags + ((size_t)t * GRP + g) * 64 + bl, 1u,
                                   __ATOMIC_RELAXED, __HIP_MEMORY_SCOPE_AGENT);
        }
    }
}

// ---------------- tag head: out = hs·out_w^T + out_b (MFMA) ------------------
// 80 blocks x 4 waves; block = timestep t, wave wv = 16 tags, m-tile = group
__global__ __launch_bounds__(256) void tag_kernel(
    const short* __restrict__ hst, const short* __restrict__ outw_bf,
    const float* __restrict__ out_b, float* __restrict__ out)
{
    const int tid = threadIdx.x;
    const int l = tid & 63, wv = tid >> 6;
    const int t = blockIdx.x;
    const int n0 = wv * 16;
    const int lr = l & 15, lh = l >> 4;

    const short* At = hst + (size_t)t * HSTEP;
    const short* Bw = outw_bf + (size_t)(n0 + lr) * HH + lh * 8;

    floatx4 acc[4];
    #pragma unroll
    for (int m = 0; m < 4; ++m) acc[m] = (floatx4)0.f;

    #pragma unroll 4
    for (int kk = 0; kk < 32; ++kk) {
        short8 b = *(const short8*)(Bw + kk * 32);
        #pragma unroll
        for (int m = 0; m < 4; ++m) {
            short8 a = *(const short8*)(At + m * 16384 + kk * 512 + l * 8);
            acc[m] = __builtin_amdgcn_mfma_f32_16x16x32_bf16(a, b, acc[m], 0, 0, 0);
        }
    }
    int col = n0 + lr;
    if (col < TAGS) {
        float bias = out_b[col];
        #pragma unroll
        for (int m = 0; m < 4; ++m)
            #pragma unroll
            for (int q = 0; q < 4; ++q) {
                int row = t * 64 + m * 16 + lh * 4 + q;   // flat row r = t*64+b
                out[(size_t)row * TAGS + col] = acc[m][q] + bias;
            }
    }
}

// ---------------- log_softmax over the P axis, in place ----------------------
__global__ __launch_bounds__(256) void logsoftmax_kernel(float* __restrict__ out)
{
    const int tid = threadIdx.x;
    const int lane = tid & 63;
    const int pair = blockIdx.x * 4 + (tid >> 6);
    if (pair >= BB * TAGS) return;
    const int bb = pair / TAGS, g = pair % TAGS;
    float* base = out + (size_t)bb * PP * TAGS + g;
    float v0 = base[lane * TAGS];
    float v1 = (lane < PP - 64) ? base[(lane + 64) * TAGS] : -1e30f;
    float m = fmaxf(v0, v1);
    for (int off = 32; off > 0; off >>= 1) m = fmaxf(m, __shfl_xor(m, off, 64));
    float s = __expf(v0 - m) + ((lane < PP - 64) ? __expf(v1 - m) : 0.f);
    s = wave_reduce_sum(s);
    float lz = m + __logf(s);
    base[lane * TAGS] = v0 - lz;
    if (lane < PP - 64) base[(lane + 64) * TAGS] = v1 - lz;
}

extern "C" void kernel_launch(void* const* d_in, const int* in_sizes, int n_in,
                              void* d_out, int out_size, void* d_ws, size_t ws_size,
                              hipStream_t stream)
{
    const int*   sent     = (const int*)d_in[0];
    const int*   chars    = (const int*)d_in[1];
    const float* word_emb = (const float*)d_in[2];
    const float* char_emb = (const float*)d_in[3];
    const float* conv_w   = (const float*)d_in[4];
    const float* conv_b   = (const float*)d_in[5];
    const float* w_ih     = (const float*)d_in[6];
    const float* w_hh     = (const float*)d_in[7];
    const float* b_ih     = (const float*)d_in[8];
    const float* b_hh     = (const float*)d_in[9];
    const float* out_w    = (const float*)d_in[10];
    const float* out_b    = (const float*)d_in[11];
    float* out = (float*)d_out;

    short* X_bf    = (short*)d_ws;                             // 5120*288
    short* wih_bf  = X_bf + (size_t)ROWS * KPAD;               // 4096*288
    short* wpk     = wih_bf + (size_t)NG * KPAD;               // 4096*1024 (frag-major)
    short* outw_bf = wpk + (size_t)NG * HH;                    // 64*1024
    short* ginP    = outw_bf + (size_t)64 * HH;                // 4096*5120
    short* hst     = ginP + (size_t)NG * ROWS;                 // 80*HSTEP
    unsigned* flags = (unsigned*)(hst + (size_t)PP * HSTEP);   // 80*4*64 words

    hipLaunchKernelGGL(prep_kernel, dim3(2048), dim3(256), 0, stream,
                       w_ih, w_hh, out_w, wih_bf, wpk, outw_bf, flags);
    hipLaunchKernelGGL(embed_kernel, dim3(ROWS), dim3(256), 0, stream,
                       sent, chars, word_emb, char_emb, conv_w, conv_b, X_bf);
    hipLaunchKernelGGL(gemm_in_kernel, dim3(ROWS / 64, NG / 128), dim3(256), 0, stream,
                       X_bf, wih_bf, b_ih, b_hh, ginP);
    {
        void* kargs[4] = { (void*)&hst, (void*)&wpk, (void*)&ginP, (void*)&flags };
        hipLaunchCooperativeKernel((void*)lstm_seq_kernel, dim3(NBLK), dim3(256),
                                   kargs, 0, stream);
    }
    hipLaunchKernelGGL(tag_kernel, dim3(PP), dim3(256), 0, stream,
                       hst, outw_bf, out_b, out);
    hipLaunchKernelGGL(logsoftmax_kernel, dim3((BB * TAGS + 3) / 4), dim3(256), 0, stream,
                       out);
}

// Round 6
// 537.618 us; speedup vs baseline: 7.5406x; 2.9812x over previous
//
#include <hip/hip_runtime.h>
#include <math.h>

#define BB 64
#define PP 80
#define LC 18
#define EE 256
#define HH 1024
#define LCH 4
#define KW 3
#define TAGS 50
#define DD 260          // EE + LCH
#define KPAD 288        // DD padded to multiple of 32
#define ROWS (BB*PP)    // 5120
#define WN (LC-KW+1)    // 16
#define NG (4*HH)       // 4096 gate rows
#define GRP 4           // batch groups (16 batches each)
#define NBLK (GRP*64)   // 256 persistent blocks
#define HSTEP (GRP*32*512) // shorts per timestep of hst: [4 g][32 kk][64 lane][8 e]

typedef __attribute__((ext_vector_type(8))) short short8;   // 8 x bf16
typedef __attribute__((ext_vector_type(4))) short short4v;  // 4 x bf16 (8B store)
typedef __attribute__((ext_vector_type(4))) float floatx4;  // MFMA acc
typedef __attribute__((ext_vector_type(4))) int int4v;      // 16B asm payload

__device__ __forceinline__ short f2bf(float x) {
    unsigned u = __float_as_uint(x);
    unsigned r = (u + 0x7FFFu + ((u >> 16) & 1u)) >> 16;
    return (short)r;
}
__device__ __forceinline__ float bf2f(short s) {
    return __uint_as_float(((unsigned)(unsigned short)s) << 16);
}
__device__ __forceinline__ float sigf(float x) { return 1.f / (1.f + __expf(-x)); }
__device__ __forceinline__ float tanhfast(float x) {
    float e = __expf(2.f * x);
    return 1.f - 2.f / (e + 1.f);
}
__device__ __forceinline__ float wave_reduce_sum(float v) {
    for (int off = 32; off > 0; off >>= 1) v += __shfl_xor(v, off, 64);
    return v;
}

// ---- prep: wih pad->bf16, whh -> fragment-major pack, outw pad, flags zero --
__global__ __launch_bounds__(256) void prep_kernel(
    const float* __restrict__ wih, const float* __restrict__ whh,
    const float* __restrict__ outw,
    short* __restrict__ wih_bf, short* __restrict__ wpk,
    short* __restrict__ outw_bf, unsigned* __restrict__ flags)
{
    const int NI = NG * KPAD;       // 1179648
    const int NH = NG * HH;         // 4194304
    const int NO = 64 * HH;         // 65536
    const int total = NI + NH + NO;
    for (int i = blockIdx.x * 256 + threadIdx.x; i < total; i += gridDim.x * 256) {
        if (i < NI) {
            int r = i / KPAD, c = i - r * KPAD;
            wih_bf[i] = (c < DD) ? f2bf(wih[r * DD + c]) : (short)0;
        } else if (i < NI + NH) {
            int o = i - NI;
            // wpk[bl][w][kk][lane][e] <- whh[w*1024 + bl*16 + (l&15)][kk*32+(l>>4)*8+e]
            int e  = o & 7;
            int l  = (o >> 3) & 63;
            int kk = (o >> 9) & 31;
            int w  = (o >> 14) & 3;
            int bl = o >> 16;
            int row = w * HH + bl * 16 + (l & 15);
            int col = kk * 32 + (l >> 4) * 8 + e;
            wpk[o] = f2bf(whh[(size_t)row * HH + col]);
        } else {
            int k = i - NI - NH;
            int r = k >> 10;
            outw_bf[k] = (r < TAGS) ? f2bf(outw[k]) : (short)0;
        }
    }
    // zero sync flags (timestep-indexed; must be re-zeroed every launch)
    for (int i = blockIdx.x * 256 + threadIdx.x; i < PP * GRP * 64; i += gridDim.x * 256)
        flags[i] = 0u;
}

// ---------------- embedding + char CNN -> X bf16 [5120][288] ----------------
__global__ __launch_bounds__(256) void embed_kernel(
    const int* __restrict__ sent, const int* __restrict__ chars,
    const float* __restrict__ word_emb, const float* __restrict__ char_emb,
    const float* __restrict__ conv_w, const float* __restrict__ conv_b,
    short* __restrict__ X)
{
    __shared__ float4 ce[LC * 64];
    __shared__ float phi[WN * LCH];
    __shared__ float charrep[LCH];
    const int r = blockIdx.x;
    const int t = threadIdx.x;
    const int lane = t & 63, wv = t >> 6;

    const int cbase = r * LC;
    for (int i = 0; i < 5; ++i) {
        int idx = i * 256 + t;
        if (idx < LC * 64) {
            int j = idx >> 6, e4 = idx & 63;
            int ch = chars[cbase + j];
            ce[idx] = ((const float4*)(char_emb + (size_t)ch * EE))[e4];
        }
    }
    float4 cw[KW][LCH];
    #pragma unroll
    for (int k = 0; k < KW; ++k)
        #pragma unroll
        for (int c = 0; c < LCH; ++c)
            cw[k][c] = ((const float4*)(conv_w + c * (KW * EE) + k * EE))[lane];
    __syncthreads();

    #pragma unroll
    for (int wi = 0; wi < 4; ++wi) {
        int w = wv + wi * 4;
        float acc[LCH] = {0.f, 0.f, 0.f, 0.f};
        #pragma unroll
        for (int k = 0; k < KW; ++k) {
            float4 v = ce[(w + k) * 64 + lane];
            #pragma unroll
            for (int c = 0; c < LCH; ++c)
                acc[c] += v.x * cw[k][c].x + v.y * cw[k][c].y +
                          v.z * cw[k][c].z + v.w * cw[k][c].w;
        }
        #pragma unroll
        for (int c = 0; c < LCH; ++c) {
            float s = wave_reduce_sum(acc[c]);
            if (lane == 0) phi[w * LCH + c] = s;
        }
    }
    __syncthreads();
    if (t < LCH) {
        float m = -1e30f;
        for (int w = 0; w < WN; ++w) m = fmaxf(m, phi[w * LCH + t]);
        charrep[t] = m + conv_b[t];
    }
    __syncthreads();

    const int word = sent[r];
    X[(size_t)r * KPAD + t] = f2bf(word_emb[(size_t)word * EE + t]);
    if (t < LCH) X[(size_t)r * KPAD + EE + t] = f2bf(charrep[t]);
    if (t >= 228) X[(size_t)r * KPAD + 32 + t] = (short)0;
}

// ---- input GEMM -> ginP[t][g][bl][gate][uu][b16] (coalesced per-step read) --
__global__ __launch_bounds__(256) void gemm_in_kernel(
    const short* __restrict__ X, const short* __restrict__ Wih,
    const float* __restrict__ b_ih, const float* __restrict__ b_hh,
    short* __restrict__ ginP)
{
    const int tid = threadIdx.x;
    const int l = tid & 63, wv = tid >> 6;
    const int r0 = blockIdx.x * 64;          // rows = t*64 + b
    const int n0 = blockIdx.y * 128 + wv * 32;
    const int lr = l & 15, lh = l >> 4;

    floatx4 acc[4][2];
    #pragma unroll
    for (int m = 0; m < 4; ++m)
        #pragma unroll
        for (int n = 0; n < 2; ++n) acc[m][n] = (floatx4)0.f;

    const short* Xb = X + (size_t)(r0 + lr) * KPAD + lh * 8;
    const short* Wb = Wih + (size_t)(n0 + lr) * KPAD + lh * 8;

    #pragma unroll
    for (int k0 = 0; k0 < KPAD; k0 += 32) {
        short8 a0 = *(const short8*)(Xb + k0);
        short8 a1 = *(const short8*)(Xb + 16 * KPAD + k0);
        short8 a2 = *(const short8*)(Xb + 32 * KPAD + k0);
        short8 a3 = *(const short8*)(Xb + 48 * KPAD + k0);
        short8 b0 = *(const short8*)(Wb + k0);
        short8 b1 = *(const short8*)(Wb + 16 * KPAD + k0);
        acc[0][0] = __builtin_amdgcn_mfma_f32_16x16x32_bf16(a0, b0, acc[0][0], 0, 0, 0);
        acc[1][0] = __builtin_amdgcn_mfma_f32_16x16x32_bf16(a1, b0, acc[1][0], 0, 0, 0);
        acc[2][0] = __builtin_amdgcn_mfma_f32_16x16x32_bf16(a2, b0, acc[2][0], 0, 0, 0);
        acc[3][0] = __builtin_amdgcn_mfma_f32_16x16x32_bf16(a3, b0, acc[3][0], 0, 0, 0);
        acc[0][1] = __builtin_amdgcn_mfma_f32_16x16x32_bf16(a0, b1, acc[0][1], 0, 0, 0);
        acc[1][1] = __builtin_amdgcn_mfma_f32_16x16x32_bf16(a1, b1, acc[1][1], 0, 0, 0);
        acc[2][1] = __builtin_amdgcn_mfma_f32_16x16x32_bf16(a2, b1, acc[2][1], 0, 0, 0);
        acc[3][1] = __builtin_amdgcn_mfma_f32_16x16x32_bf16(a3, b1, acc[3][1], 0, 0, 0);
    }
    // rows r0+m*16+lh*4+q: t=blockIdx.x, g=m, b16=lh*4+q
    #pragma unroll
    for (int m = 0; m < 4; ++m)
        #pragma unroll
        for (int n = 0; n < 2; ++n) {
            int col = n0 + n * 16 + lr;            // gate-unit index 0..4095
            float bias = b_ih[col] + b_hh[col];
            short4v pack;
            #pragma unroll
            for (int q = 0; q < 4; ++q) pack[q] = f2bf(acc[m][n][q] + bias);
            int w_ = col >> 10, bl_ = (col >> 4) & 63, uu_ = col & 15;
            size_t addr = ((((size_t)(blockIdx.x * GRP + m) * 64 + bl_) * 4 + w_) * 16
                           + uu_) * 16 + lh * 4;
            *(short4v*)(ginP + addr) = pack;
        }
}

// ---------------- persistent LSTM: IF-bypass h exchange, no fences -----------
// 256 blocks x 256 thr. Block = (g = bid>>6 batch group, bl = bid&63 unit blk).
// Wave w = gate w; 16 units x K=1024 weights resident in registers.
// hst[t] layout: [4 g][32 kk][64 lane][8 e] bf16; h traffic via sc0 sc1 (IF).
__global__ __launch_bounds__(256, 1) void lstm_seq_kernel(
    short* __restrict__ hst, const short* __restrict__ wpk,
    const short* __restrict__ ginP, unsigned* __restrict__ flags)
{
    __shared__ float lds_g[4][16][20];
    __shared__ short8 hbufv[16][2];

    const int tid = threadIdx.x;
    const int l = tid & 63;
    const int w = tid >> 6;             // wave = gate
    const int g  = blockIdx.x >> 6;     // batch group (16 batches)
    const int bl = blockIdx.x & 63;     // unit block (16 units)

    // resident recurrent weights: 32x short8 (same pack as before)
    short8 barr[32];
    const short* wb = wpk + ((size_t)(bl * 4 + w) * 32) * 512 + l * 8;
    #pragma unroll
    for (int kk = 0; kk < 32; ++kk)
        barr[kk] = *(const short8*)(wb + kk * 512);

    const int b16 = tid & 15;           // epilogue: batch within group
    const int uu  = tid >> 4;           // epilogue: unit 0..15
    float c = 0.f;

    // gin for t=0
    float gv[4];
    {
        const short* gb = ginP + (((size_t)g * 64 + bl) * 4) * 256 + uu * 16 + b16;
        #pragma unroll
        for (int q = 0; q < 4; ++q) gv[q] = bf2f(gb[q * 256]);
    }

    for (int t = 0; t < PP; ++t) {
        if (t > 0) {
            // wait for all 64 producer blocks of this group, one flag per lane
            if (tid < 64) {
                const unsigned* fl = flags + ((size_t)(t - 1) * GRP + g) * 64;
                while (__hip_atomic_load(fl + tid, __ATOMIC_RELAXED,
                                         __HIP_MEMORY_SCOPE_AGENT) == 0u)
                    __builtin_amdgcn_s_sleep(1);
            }
            __syncthreads();

            // h loads bypass L2 (coherent at IF) — issue all 32, wait once
            const short* A = hst + (size_t)(t - 1) * HSTEP + g * 16384;
            int4v a[32];
            #pragma unroll
            for (int kk = 0; kk < 32; ++kk) {
                const short* ap = A + kk * 512 + l * 8;
                asm volatile("global_load_dwordx4 %0, %1, off sc0 sc1"
                             : "=v"(a[kk]) : "v"(ap) : "memory");
            }
            asm volatile("s_waitcnt vmcnt(0)" ::: "memory");
            __builtin_amdgcn_sched_barrier(0);

            floatx4 acc = (floatx4)0.f;
            #pragma unroll
            for (int kk = 0; kk < 32; ++kk)
                acc = __builtin_amdgcn_mfma_f32_16x16x32_bf16(
                    __builtin_bit_cast(short8, a[kk]), barr[kk], acc, 0, 0, 0);
            #pragma unroll
            for (int q = 0; q < 4; ++q)
                lds_g[w][(l >> 4) * 4 + q][l & 15] = acc[q];
            __syncthreads();
        }

        // fused gate epilogue: thread owns (batch b16, unit u0+uu)
        float s0 = gv[0], s1 = gv[1], s2 = gv[2], s3 = gv[3];
        if (t > 0) {
            s0 += lds_g[0][b16][uu];
            s1 += lds_g[1][b16][uu];
            s2 += lds_g[2][b16][uu];
            s3 += lds_g[3][b16][uu];
        }
        float i_ = sigf(s0), f_ = sigf(s1), g_ = tanhfast(s2), o_ = sigf(s3);
        c = f_ * c + i_ * g_;
        ((short*)&hbufv[b16][0])[uu] = f2bf(o_ * tanhfast(c));

        // prefetch gin for t+1 (hidden under store/poll)
        if (t + 1 < PP) {
            const short* gb = ginP + (((size_t)(t + 1) * GRP + g) * 64 + bl) * 1024
                              + uu * 16 + b16;
            #pragma unroll
            for (int q = 0; q < 4; ++q) gv[q] = bf2f(gb[q * 256]);
        }
        __syncthreads();

        // h store bypasses L2 (write-through to IF): 32 lanes x 16B
        if (tid < 32) {
            int lh8 = tid >> 4, bb = tid & 15;
            int4v hv = __builtin_bit_cast(int4v, hbufv[bb][lh8]);
            int lt = ((2 * bl + lh8) & 3) * 16 + bb;
            short* hp = hst + (size_t)t * HSTEP + g * 16384 + (bl >> 1) * 512 + lt * 8;
            asm volatile("global_store_dwordx4 %0, %1, off sc0 sc1"
                         :: "v"(hp), "v"(hv) : "memory");
        }
        if (t + 1 < PP && w == 0) {
            asm volatile("s_waitcnt vmcnt(0)" ::: "memory");  // h at IF before flag
            if (tid == 0)
                __hip_atomic_store(flags + ((size_t)t * GRP + g) * 64 + bl, 1u,
                                   __ATOMIC_RELAXED, __HIP_MEMORY_SCOPE_AGENT);
        }
    }
}

// ---------------- tag head: out = hs·out_w^T + out_b (MFMA) ------------------
// 80 blocks x 4 waves; block = timestep t, wave wv = 16 tags, m-tile = group
__global__ __launch_bounds__(256) void tag_kernel(
    const short* __restrict__ hst, const short* __restrict__ outw_bf,
    const float* __restrict__ out_b, float* __restrict__ out)
{
    const int tid = threadIdx.x;
    const int l = tid & 63, wv = tid >> 6;
    const int t = blockIdx.x;
    const int n0 = wv * 16;
    const int lr = l & 15, lh = l >> 4;

    const short* At = hst + (size_t)t * HSTEP;
    const short* Bw = outw_bf + (size_t)(n0 + lr) * HH + lh * 8;

    floatx4 acc[4];
    #pragma unroll
    for (int m = 0; m < 4; ++m) acc[m] = (floatx4)0.f;

    #pragma unroll 4
    for (int kk = 0; kk < 32; ++kk) {
        short8 b = *(const short8*)(Bw + kk * 32);
        #pragma unroll
        for (int m = 0; m < 4; ++m) {
            short8 a = *(const short8*)(At + m * 16384 + kk * 512 + l * 8);
            acc[m] = __builtin_amdgcn_mfma_f32_16x16x32_bf16(a, b, acc[m], 0, 0, 0);
        }
    }
    int col = n0 + lr;
    if (col < TAGS) {
        float bias = out_b[col];
        #pragma unroll
        for (int m = 0; m < 4; ++m)
            #pragma unroll
            for (int q = 0; q < 4; ++q) {
                int row = t * 64 + m * 16 + lh * 4 + q;   // flat row r = t*64+b
                out[(size_t)row * TAGS + col] = acc[m][q] + bias;
            }
    }
}

// ---------------- log_softmax over the P axis, in place ----------------------
__global__ __launch_bounds__(256) void logsoftmax_kernel(float* __restrict__ out)
{
    const int tid = threadIdx.x;
    const int lane = tid & 63;
    const int pair = blockIdx.x * 4 + (tid >> 6);
    if (pair >= BB * TAGS) return;
    const int bb = pair / TAGS, g = pair % TAGS;
    float* base = out + (size_t)bb * PP * TAGS + g;
    float v0 = base[lane * TAGS];
    float v1 = (lane < PP - 64) ? base[(lane + 64) * TAGS] : -1e30f;
    float m = fmaxf(v0, v1);
    for (int off = 32; off > 0; off >>= 1) m = fmaxf(m, __shfl_xor(m, off, 64));
    float s = __expf(v0 - m) + ((lane < PP - 64) ? __expf(v1 - m) : 0.f);
    s = wave_reduce_sum(s);
    float lz = m + __logf(s);
    base[lane * TAGS] = v0 - lz;
    if (lane < PP - 64) base[(lane + 64) * TAGS] = v1 - lz;
}

extern "C" void kernel_launch(void* const* d_in, const int* in_sizes, int n_in,
                              void* d_out, int out_size, void* d_ws, size_t ws_size,
                              hipStream_t stream)
{
    const int*   sent     = (const int*)d_in[0];
    const int*   chars    = (const int*)d_in[1];
    const float* word_emb = (const float*)d_in[2];
    const float* char_emb = (const float*)d_in[3];
    const float* conv_w   = (const float*)d_in[4];
    const float* conv_b   = (const float*)d_in[5];
    const float* w_ih     = (const float*)d_in[6];
    const float* w_hh     = (const float*)d_in[7];
    const float* b_ih     = (const float*)d_in[8];
    const float* b_hh     = (const float*)d_in[9];
    const float* out_w    = (const float*)d_in[10];
    const float* out_b    = (const float*)d_in[11];
    float* out = (float*)d_out;

    short* X_bf    = (short*)d_ws;                             // 5120*288
    short* wih_bf  = X_bf + (size_t)ROWS * KPAD;               // 4096*288
    short* wpk     = wih_bf + (size_t)NG * KPAD;               // 4096*1024 (frag-major)
    short* outw_bf = wpk + (size_t)NG * HH;                    // 64*1024
    short* ginP    = outw_bf + (size_t)64 * HH;                // 4096*5120
    short* hst     = ginP + (size_t)NG * ROWS;                 // 80*HSTEP
    unsigned* flags = (unsigned*)(hst + (size_t)PP * HSTEP);   // 80*4*64 words

    hipLaunchKernelGGL(prep_kernel, dim3(2048), dim3(256), 0, stream,
                       w_ih, w_hh, out_w, wih_bf, wpk, outw_bf, flags);
    hipLaunchKernelGGL(embed_kernel, dim3(ROWS), dim3(256), 0, stream,
                       sent, chars, word_emb, char_emb, conv_w, conv_b, X_bf);
    hipLaunchKernelGGL(gemm_in_kernel, dim3(ROWS / 64, NG / 128), dim3(256), 0, stream,
                       X_bf, wih_bf, b_ih, b_hh, ginP);
    {
        void* kargs[4] = { (void*)&hst, (void*)&wpk, (void*)&ginP, (void*)&flags };
        hipLaunchCooperativeKernel((void*)lstm_seq_kernel, dim3(NBLK), dim3(256),
                                   kargs, 0, stream);
    }
    hipLaunchKernelGGL(tag_kernel, dim3(PP), dim3(256), 0, stream,
                       hst, outw_bf, out_b, out);
    hipLaunchKernelGGL(logsoftmax_kernel, dim3((BB * TAGS + 3) / 4), dim3(256), 0, stream,
                       out);
}

// Round 7
// 485.859 us; speedup vs baseline: 8.3439x; 1.1065x over previous
//
#include <hip/hip_runtime.h>
#include <math.h>

#define BB 64
#define PP 80
#define LC 18
#define EE 256
#define HH 1024
#define LCH 4
#define KW 3
#define TAGS 50
#define DD 260          // EE + LCH
#define KPAD 288        // DD padded to multiple of 32
#define ROWS (BB*PP)    // 5120
#define WN (LC-KW+1)    // 16
#define NG (4*HH)       // 4096 gate rows
#define GRP 4           // batch groups (16 batches each)
#define NBLK (GRP*64)   // 256 persistent blocks
#define HSTEP (GRP*32*512) // shorts per timestep of hst: [4 g][32 kk][64 lane][8 e]

typedef __attribute__((ext_vector_type(8))) short short8;   // 8 x bf16
typedef __attribute__((ext_vector_type(4))) short short4v;  // 4 x bf16 (8B store)
typedef __attribute__((ext_vector_type(4))) float floatx4;  // MFMA acc
typedef __attribute__((ext_vector_type(4))) int int4v;      // 16B asm payload

__device__ __forceinline__ short f2bf(float x) {
    unsigned u = __float_as_uint(x);
    unsigned r = (u + 0x7FFFu + ((u >> 16) & 1u)) >> 16;
    return (short)r;
}
__device__ __forceinline__ float bf2f(short s) {
    return __uint_as_float(((unsigned)(unsigned short)s) << 16);
}
__device__ __forceinline__ float sigf(float x) { return 1.f / (1.f + __expf(-x)); }
__device__ __forceinline__ float tanhfast(float x) {
    float e = __expf(2.f * x);
    return 1.f - 2.f / (e + 1.f);
}
__device__ __forceinline__ float wave_reduce_sum(float v) {
    for (int off = 32; off > 0; off >>= 1) v += __shfl_xor(v, off, 64);
    return v;
}

// ---- prep: wih pad->bf16, whh -> K-split fragment pack, outw pad, flags -----
__global__ __launch_bounds__(256) void prep_kernel(
    const float* __restrict__ wih, const float* __restrict__ whh,
    const float* __restrict__ outw,
    short* __restrict__ wih_bf, short* __restrict__ wpk,
    short* __restrict__ outw_bf, unsigned* __restrict__ flags)
{
    const int NI = NG * KPAD;       // 1179648
    const int NH = NG * HH;         // 4194304
    const int NO = 64 * HH;         // 65536
    const int total = NI + NH + NO;
    for (int i = blockIdx.x * 256 + threadIdx.x; i < total; i += gridDim.x * 256) {
        if (i < NI) {
            int r = i / KPAD, c = i - r * KPAD;
            wih_bf[i] = (c < DD) ? f2bf(wih[r * DD + c]) : (short)0;
        } else if (i < NI + NH) {
            int o = i - NI;
            // wpk[bl][w][tl][s][lane][e] <- whh[tl*HH + bl*16 + (l&15)]
            //                                  [w*128 + s*32 + (l>>4)*8 + e]
            int e  = o & 7;
            int l  = (o >> 3) & 63;
            int s  = (o >> 9) & 3;
            int tl = (o >> 11) & 3;
            int w  = (o >> 13) & 7;
            int bl = o >> 16;
            int row = tl * HH + bl * 16 + (l & 15);
            int col = w * 128 + s * 32 + (l >> 4) * 8 + e;
            wpk[o] = f2bf(whh[(size_t)row * HH + col]);
        } else {
            int k = i - NI - NH;
            int r = k >> 10;
            outw_bf[k] = (r < TAGS) ? f2bf(outw[k]) : (short)0;
        }
    }
    // zero sync flags (timestep-indexed; must be re-zeroed every launch)
    for (int i = blockIdx.x * 256 + threadIdx.x; i < PP * GRP * 64; i += gridDim.x * 256)
        flags[i] = 0u;
}

// ---------------- embedding + char CNN -> X bf16 [5120][288] ----------------
__global__ __launch_bounds__(256) void embed_kernel(
    const int* __restrict__ sent, const int* __restrict__ chars,
    const float* __restrict__ word_emb, const float* __restrict__ char_emb,
    const float* __restrict__ conv_w, const float* __restrict__ conv_b,
    short* __restrict__ X)
{
    __shared__ float4 ce[LC * 64];
    __shared__ float phi[WN * LCH];
    __shared__ float charrep[LCH];
    const int r = blockIdx.x;
    const int t = threadIdx.x;
    const int lane = t & 63, wv = t >> 6;

    const int cbase = r * LC;
    for (int i = 0; i < 5; ++i) {
        int idx = i * 256 + t;
        if (idx < LC * 64) {
            int j = idx >> 6, e4 = idx & 63;
            int ch = chars[cbase + j];
            ce[idx] = ((const float4*)(char_emb + (size_t)ch * EE))[e4];
        }
    }
    float4 cw[KW][LCH];
    #pragma unroll
    for (int k = 0; k < KW; ++k)
        #pragma unroll
        for (int c = 0; c < LCH; ++c)
            cw[k][c] = ((const float4*)(conv_w + c * (KW * EE) + k * EE))[lane];
    __syncthreads();

    #pragma unroll
    for (int wi = 0; wi < 4; ++wi) {
        int w = wv + wi * 4;
        float acc[LCH] = {0.f, 0.f, 0.f, 0.f};
        #pragma unroll
        for (int k = 0; k < KW; ++k) {
            float4 v = ce[(w + k) * 64 + lane];
            #pragma unroll
            for (int c = 0; c < LCH; ++c)
                acc[c] += v.x * cw[k][c].x + v.y * cw[k][c].y +
                          v.z * cw[k][c].z + v.w * cw[k][c].w;
        }
        #pragma unroll
        for (int c = 0; c < LCH; ++c) {
            float s = wave_reduce_sum(acc[c]);
            if (lane == 0) phi[w * LCH + c] = s;
        }
    }
    __syncthreads();
    if (t < LCH) {
        float m = -1e30f;
        for (int w = 0; w < WN; ++w) m = fmaxf(m, phi[w * LCH + t]);
        charrep[t] = m + conv_b[t];
    }
    __syncthreads();

    const int word = sent[r];
    X[(size_t)r * KPAD + t] = f2bf(word_emb[(size_t)word * EE + t]);
    if (t < LCH) X[(size_t)r * KPAD + EE + t] = f2bf(charrep[t]);
    if (t >= 228) X[(size_t)r * KPAD + 32 + t] = (short)0;
}

// ---- input GEMM -> ginP[t][g][bl][gate][uu][b16] (coalesced per-step read) --
__global__ __launch_bounds__(256) void gemm_in_kernel(
    const short* __restrict__ X, const short* __restrict__ Wih,
    const float* __restrict__ b_ih, const float* __restrict__ b_hh,
    short* __restrict__ ginP)
{
    const int tid = threadIdx.x;
    const int l = tid & 63, wv = tid >> 6;
    const int r0 = blockIdx.x * 64;          // rows = t*64 + b
    const int n0 = blockIdx.y * 128 + wv * 32;
    const int lr = l & 15, lh = l >> 4;

    floatx4 acc[4][2];
    #pragma unroll
    for (int m = 0; m < 4; ++m)
        #pragma unroll
        for (int n = 0; n < 2; ++n) acc[m][n] = (floatx4)0.f;

    const short* Xb = X + (size_t)(r0 + lr) * KPAD + lh * 8;
    const short* Wb = Wih + (size_t)(n0 + lr) * KPAD + lh * 8;

    #pragma unroll
    for (int k0 = 0; k0 < KPAD; k0 += 32) {
        short8 a0 = *(const short8*)(Xb + k0);
        short8 a1 = *(const short8*)(Xb + 16 * KPAD + k0);
        short8 a2 = *(const short8*)(Xb + 32 * KPAD + k0);
        short8 a3 = *(const short8*)(Xb + 48 * KPAD + k0);
        short8 b0 = *(const short8*)(Wb + k0);
        short8 b1 = *(const short8*)(Wb + 16 * KPAD + k0);
        acc[0][0] = __builtin_amdgcn_mfma_f32_16x16x32_bf16(a0, b0, acc[0][0], 0, 0, 0);
        acc[1][0] = __builtin_amdgcn_mfma_f32_16x16x32_bf16(a1, b0, acc[1][0], 0, 0, 0);
        acc[2][0] = __builtin_amdgcn_mfma_f32_16x16x32_bf16(a2, b0, acc[2][0], 0, 0, 0);
        acc[3][0] = __builtin_amdgcn_mfma_f32_16x16x32_bf16(a3, b0, acc[3][0], 0, 0, 0);
        acc[0][1] = __builtin_amdgcn_mfma_f32_16x16x32_bf16(a0, b1, acc[0][1], 0, 0, 0);
        acc[1][1] = __builtin_amdgcn_mfma_f32_16x16x32_bf16(a1, b1, acc[1][1], 0, 0, 0);
        acc[2][1] = __builtin_amdgcn_mfma_f32_16x16x32_bf16(a2, b1, acc[2][1], 0, 0, 0);
        acc[3][1] = __builtin_amdgcn_mfma_f32_16x16x32_bf16(a3, b1, acc[3][1], 0, 0, 0);
    }
    // rows r0+m*16+lh*4+q: t=blockIdx.x, g=m, b16=lh*4+q
    #pragma unroll
    for (int m = 0; m < 4; ++m)
        #pragma unroll
        for (int n = 0; n < 2; ++n) {
            int col = n0 + n * 16 + lr;            // gate-unit index 0..4095
            float bias = b_ih[col] + b_hh[col];
            short4v pack;
            #pragma unroll
            for (int q = 0; q < 4; ++q) pack[q] = f2bf(acc[m][n][q] + bias);
            int w_ = col >> 10, bl_ = (col >> 4) & 63, uu_ = col & 15;
            size_t addr = ((((size_t)(blockIdx.x * GRP + m) * 64 + bl_) * 4 + w_) * 16
                           + uu_) * 16 + lh * 4;
            *(short4v*)(ginP + addr) = pack;
        }
}

// ---------------- persistent LSTM: 8-wave K-split, dedup loads, IF exchange --
// 256 blocks x 512 thr. Block = (g = bid>>6, bl = bid&63: units bl*16..+15).
// Wave w owns K-chunk w*128 for all 128 gate-rows (4 tiles x 4 ksub in regs).
// Cross-wave K-reduce in LDS; poll on wave 1 overlaps wave-0 store-ack.
__global__ __launch_bounds__(512, 1) void lstm_seq_kernel(
    short* __restrict__ hst, const short* __restrict__ wpk,
    const short* __restrict__ ginP, unsigned* __restrict__ flags)
{
    __shared__ __align__(16) float lds_g[8][4][16][20];
    __shared__ short8 hbufv[16][2];

    const int tid = threadIdx.x;
    const int l = tid & 63;
    const int w = tid >> 6;             // wave 0..7 = K-chunk id
    const int g  = blockIdx.x >> 6;     // batch group (16 batches)
    const int bl = blockIdx.x & 63;     // unit block (16 units)

    // resident weights: wave w holds (4 gates x 16 units) x K-chunk w*128
    short8 barr[4][4];
    {
        const short* wb = wpk + ((size_t)(bl * 8 + w) * 16) * 512 + l * 8;
        #pragma unroll
        for (int tl = 0; tl < 4; ++tl)
            #pragma unroll
            for (int s = 0; s < 4; ++s)
                barr[tl][s] = *(const short8*)(wb + (tl * 4 + s) * 512);
    }

    const int b16 = tid & 15;           // epilogue: batch (tid<256)
    const int uu  = (tid >> 4) & 15;    // epilogue: unit
    float c = 0.f;

    float gv[4] = {0.f, 0.f, 0.f, 0.f};
    if (tid < 256) {
        const short* gb = ginP + (((size_t)g * 64 + bl) * 4) * 256 + uu * 16 + b16;
        #pragma unroll
        for (int q = 0; q < 4; ++q) gv[q] = bf2f(gb[q * 256]);
    }

    for (int t = 0; t < PP; ++t) {
        if (t > 0) {
            // wave 1 polls all 64 producer flags (overlaps wave-0 flag chain)
            if (tid >= 64 && tid < 128) {
                const unsigned* fl = flags + ((size_t)(t - 1) * GRP + g) * 64;
                while (__hip_atomic_load(fl + (tid - 64), __ATOMIC_RELAXED,
                                         __HIP_MEMORY_SCOPE_AGENT) == 0u)
                    __builtin_amdgcn_s_sleep(1);
            }
            __syncthreads();

            // per-wave distinct chunks kk = w*4..w*4+3 (no redundancy)
            const short* A = hst + (size_t)(t - 1) * HSTEP + g * 16384
                             + (w * 4) * 512 + l * 8;
            int4v a[4];
            #pragma unroll
            for (int s = 0; s < 4; ++s)
                asm volatile("global_load_dwordx4 %0, %1, off sc0 sc1"
                             : "=v"(a[s]) : "v"(A + s * 512) : "memory");
            asm volatile("s_waitcnt vmcnt(0)" ::: "memory");
            __builtin_amdgcn_sched_barrier(0);

            floatx4 acc[4];
            #pragma unroll
            for (int tl = 0; tl < 4; ++tl) acc[tl] = (floatx4)0.f;
            #pragma unroll
            for (int s = 0; s < 4; ++s) {
                short8 av = __builtin_bit_cast(short8, a[s]);
                #pragma unroll
                for (int tl = 0; tl < 4; ++tl)
                    acc[tl] = __builtin_amdgcn_mfma_f32_16x16x32_bf16(
                        av, barr[tl][s], acc[tl], 0, 0, 0);
            }
            // partials: lane holds cols=lr(unit), rows lh*4..+3 (batch)
            #pragma unroll
            for (int tl = 0; tl < 4; ++tl)
                *(floatx4*)&lds_g[w][tl][l & 15][(l >> 4) * 4] = acc[tl];
            __syncthreads();
        }

        if (tid < 256) {
            float s0 = gv[0], s1 = gv[1], s2 = gv[2], s3 = gv[3];
            if (t > 0) {
                #pragma unroll
                for (int w2 = 0; w2 < 8; ++w2) {
                    s0 += lds_g[w2][0][uu][b16];
                    s1 += lds_g[w2][1][uu][b16];
                    s2 += lds_g[w2][2][uu][b16];
                    s3 += lds_g[w2][3][uu][b16];
                }
            }
            float i_ = sigf(s0), f_ = sigf(s1), g_ = tanhfast(s2), o_ = sigf(s3);
            c = f_ * c + i_ * g_;
            ((short*)&hbufv[b16][0])[uu] = f2bf(o_ * tanhfast(c));

            // prefetch gin for t+1 (hidden under store/poll)
            if (t + 1 < PP) {
                const short* gb = ginP + (((size_t)(t + 1) * GRP + g) * 64 + bl) * 1024
                                  + uu * 16 + b16;
                #pragma unroll
                for (int q = 0; q < 4; ++q) gv[q] = bf2f(gb[q * 256]);
            }
        }
        __syncthreads();

        // h store bypasses L2 (write-through to IF): 32 lanes x 16B
        if (tid < 32) {
            int lh8 = tid >> 4, bb = tid & 15;
            int4v hv = __builtin_bit_cast(int4v, hbufv[bb][lh8]);
            int lt = ((2 * bl + lh8) & 3) * 16 + bb;
            short* hp = hst + (size_t)t * HSTEP + g * 16384 + (bl >> 1) * 512 + lt * 8;
            asm volatile("global_store_dwordx4 %0, %1, off sc0 sc1"
                         :: "v"(hp), "v"(hv) : "memory");
        }
        if (t + 1 < PP && w == 0) {
            asm volatile("s_waitcnt vmcnt(0)" ::: "memory");  // h at IF before flag
            if (tid == 0)
                __hip_atomic_store(flags + ((size_t)t * GRP + g) * 64 + bl, 1u,
                                   __ATOMIC_RELAXED, __HIP_MEMORY_SCOPE_AGENT);
        }
    }
}

// ---------------- tag head: out = hs·out_w^T + out_b (MFMA) ------------------
// 80 blocks x 4 waves; block = timestep t, wave wv = 16 tags, m-tile = group
__global__ __launch_bounds__(256) void tag_kernel(
    const short* __restrict__ hst, const short* __restrict__ outw_bf,
    const float* __restrict__ out_b, float* __restrict__ out)
{
    const int tid = threadIdx.x;
    const int l = tid & 63, wv = tid >> 6;
    const int t = blockIdx.x;
    const int n0 = wv * 16;
    const int lr = l & 15, lh = l >> 4;

    const short* At = hst + (size_t)t * HSTEP;
    const short* Bw = outw_bf + (size_t)(n0 + lr) * HH + lh * 8;

    floatx4 acc[4];
    #pragma unroll
    for (int m = 0; m < 4; ++m) acc[m] = (floatx4)0.f;

    #pragma unroll 4
    for (int kk = 0; kk < 32; ++kk) {
        short8 b = *(const short8*)(Bw + kk * 32);
        #pragma unroll
        for (int m = 0; m < 4; ++m) {
            short8 a = *(const short8*)(At + m * 16384 + kk * 512 + l * 8);
            acc[m] = __builtin_amdgcn_mfma_f32_16x16x32_bf16(a, b, acc[m], 0, 0, 0);
        }
    }
    int col = n0 + lr;
    if (col < TAGS) {
        float bias = out_b[col];
        #pragma unroll
        for (int m = 0; m < 4; ++m)
            #pragma unroll
            for (int q = 0; q < 4; ++q) {
                int row = t * 64 + m * 16 + lh * 4 + q;   // flat row r = t*64+b
                out[(size_t)row * TAGS + col] = acc[m][q] + bias;
            }
    }
}

// ---------------- log_softmax over the P axis, in place ----------------------
__global__ __launch_bounds__(256) void logsoftmax_kernel(float* __restrict__ out)
{
    const int tid = threadIdx.x;
    const int lane = tid & 63;
    const int pair = blockIdx.x * 4 + (tid >> 6);
    if (pair >= BB * TAGS) return;
    const int bb = pair / TAGS, g = pair % TAGS;
    float* base = out + (size_t)bb * PP * TAGS + g;
    float v0 = base[lane * TAGS];
    float v1 = (lane < PP - 64) ? base[(lane + 64) * TAGS] : -1e30f;
    float m = fmaxf(v0, v1);
    for (int off = 32; off > 0; off >>= 1) m = fmaxf(m, __shfl_xor(m, off, 64));
    float s = __expf(v0 - m) + ((lane < PP - 64) ? __expf(v1 - m) : 0.f);
    s = wave_reduce_sum(s);
    float lz = m + __logf(s);
    base[lane * TAGS] = v0 - lz;
    if (lane < PP - 64) base[(lane + 64) * TAGS] = v1 - lz;
}

extern "C" void kernel_launch(void* const* d_in, const int* in_sizes, int n_in,
                              void* d_out, int out_size, void* d_ws, size_t ws_size,
                              hipStream_t stream)
{
    const int*   sent     = (const int*)d_in[0];
    const int*   chars    = (const int*)d_in[1];
    const float* word_emb = (const float*)d_in[2];
    const float* char_emb = (const float*)d_in[3];
    const float* conv_w   = (const float*)d_in[4];
    const float* conv_b   = (const float*)d_in[5];
    const float* w_ih     = (const float*)d_in[6];
    const float* w_hh     = (const float*)d_in[7];
    const float* b_ih     = (const float*)d_in[8];
    const float* b_hh     = (const float*)d_in[9];
    const float* out_w    = (const float*)d_in[10];
    const float* out_b    = (const float*)d_in[11];
    float* out = (float*)d_out;

    short* X_bf    = (short*)d_ws;                             // 5120*288
    short* wih_bf  = X_bf + (size_t)ROWS * KPAD;               // 4096*288
    short* wpk     = wih_bf + (size_t)NG * KPAD;               // 4096*1024 (frag-major)
    short* outw_bf = wpk + (size_t)NG * HH;                    // 64*1024
    short* ginP    = outw_bf + (size_t)64 * HH;                // 4096*5120
    short* hst     = ginP + (size_t)NG * ROWS;                 // 80*HSTEP
    unsigned* flags = (unsigned*)(hst + (size_t)PP * HSTEP);   // 80*4*64 words

    hipLaunchKernelGGL(prep_kernel, dim3(2048), dim3(256), 0, stream,
                       w_ih, w_hh, out_w, wih_bf, wpk, outw_bf, flags);
    hipLaunchKernelGGL(embed_kernel, dim3(ROWS), dim3(256), 0, stream,
                       sent, chars, word_emb, char_emb, conv_w, conv_b, X_bf);
    hipLaunchKernelGGL(gemm_in_kernel, dim3(ROWS / 64, NG / 128), dim3(256), 0, stream,
                       X_bf, wih_bf, b_ih, b_hh, ginP);
    {
        void* kargs[4] = { (void*)&hst, (void*)&wpk, (void*)&ginP, (void*)&flags };
        hipLaunchCooperativeKernel((void*)lstm_seq_kernel, dim3(NBLK), dim3(512),
                                   kargs, 0, stream);
    }
    hipLaunchKernelGGL(tag_kernel, dim3(PP), dim3(256), 0, stream,
                       hst, outw_bf, out_b, out);
    hipLaunchKernelGGL(logsoftmax_kernel, dim3((BB * TAGS + 3) / 4), dim3(256), 0, stream,
                       out);
}

// Round 8
// 458.401 us; speedup vs baseline: 8.8437x; 1.0599x over previous
//
#include <hip/hip_runtime.h>
#include <math.h>

#define BB 64
#define PP 80
#define LC 18
#define EE 256
#define HH 1024
#define LCH 4
#define KW 3
#define TAGS 50
#define DD 260          // EE + LCH
#define KPAD 288        // DD padded to multiple of 32
#define ROWS (BB*PP)    // 5120
#define WN (LC-KW+1)    // 16
#define NG (4*HH)       // 4096 gate rows
#define GRP 4           // batch groups (16 batches each)
#define NBLK (GRP*64)   // 256 persistent blocks
#define HSTEP32 (GRP*32*512) // dwords per timestep: [4 g][32 kk][64 lane][8 e]

typedef __attribute__((ext_vector_type(8))) short short8;   // 8 x bf16
typedef __attribute__((ext_vector_type(4))) short short4v;  // 4 x bf16 (8B store)
typedef __attribute__((ext_vector_type(4))) float floatx4;  // MFMA acc
typedef __attribute__((ext_vector_type(4))) int int4v;      // 16B asm payload

__device__ __forceinline__ short f2bf(float x) {
    unsigned u = __float_as_uint(x);
    unsigned r = (u + 0x7FFFu + ((u >> 16) & 1u)) >> 16;
    return (short)r;
}
__device__ __forceinline__ float bf2f(short s) {
    return __uint_as_float(((unsigned)(unsigned short)s) << 16);
}
__device__ __forceinline__ float sigf(float x) { return 1.f / (1.f + __expf(-x)); }
__device__ __forceinline__ float tanhfast(float x) {
    float e = __expf(2.f * x);
    return 1.f - 2.f / (e + 1.f);
}
__device__ __forceinline__ float wave_reduce_sum(float v) {
    for (int off = 32; off > 0; off >>= 1) v += __shfl_xor(v, off, 64);
    return v;
}

// ---- prep: wih pad->bf16, whh K-split pack, outw pad, hst32 seq-clear -------
__global__ __launch_bounds__(256) void prep_kernel(
    const float* __restrict__ wih, const float* __restrict__ whh,
    const float* __restrict__ outw,
    short* __restrict__ wih_bf, short* __restrict__ wpk,
    short* __restrict__ outw_bf, unsigned* __restrict__ hst32)
{
    const int NI = NG * KPAD;       // 1179648
    const int NH = NG * HH;         // 4194304
    const int NO = 64 * HH;         // 65536
    const int total = NI + NH + NO;
    for (int i = blockIdx.x * 256 + threadIdx.x; i < total; i += gridDim.x * 256) {
        if (i < NI) {
            int r = i / KPAD, c = i - r * KPAD;
            wih_bf[i] = (c < DD) ? f2bf(wih[r * DD + c]) : (short)0;
        } else if (i < NI + NH) {
            int o = i - NI;
            // wpk[bl][w][tl][s][lane][e] <- whh[tl*HH + bl*16 + (l&15)]
            //                                  [w*128 + s*32 + (l>>4)*8 + e]
            int e  = o & 7;
            int l  = (o >> 3) & 63;
            int s  = (o >> 9) & 3;
            int tl = (o >> 11) & 3;
            int w  = (o >> 13) & 7;
            int bl = o >> 16;
            int row = tl * HH + bl * 16 + (l & 15);
            int col = w * 128 + s * 32 + (l >> 4) * 8 + e;
            wpk[o] = f2bf(whh[(size_t)row * HH + col]);
        } else {
            int k = i - NI - NH;
            int r = k >> 10;
            outw_bf[k] = (r < TAGS) ? f2bf(outw[k]) : (short)0;
        }
    }
    // clear h exchange buffer each launch: seq field 0 never matches t in [1,79]
    int4v z = {0, 0, 0, 0};
    int4v* hz = (int4v*)hst32;
    const int NZ = PP * HSTEP32 / 4;   // 1,310,720 x 16B
    for (int i = blockIdx.x * 256 + threadIdx.x; i < NZ; i += gridDim.x * 256)
        hz[i] = z;
}

// ---------------- embedding + char CNN -> X bf16 [5120][288] ----------------
__global__ __launch_bounds__(256) void embed_kernel(
    const int* __restrict__ sent, const int* __restrict__ chars,
    const float* __restrict__ word_emb, const float* __restrict__ char_emb,
    const float* __restrict__ conv_w, const float* __restrict__ conv_b,
    short* __restrict__ X)
{
    __shared__ float4 ce[LC * 64];
    __shared__ float phi[WN * LCH];
    __shared__ float charrep[LCH];
    const int r = blockIdx.x;
    const int t = threadIdx.x;
    const int lane = t & 63, wv = t >> 6;

    const int cbase = r * LC;
    for (int i = 0; i < 5; ++i) {
        int idx = i * 256 + t;
        if (idx < LC * 64) {
            int j = idx >> 6, e4 = idx & 63;
            int ch = chars[cbase + j];
            ce[idx] = ((const float4*)(char_emb + (size_t)ch * EE))[e4];
        }
    }
    float4 cw[KW][LCH];
    #pragma unroll
    for (int k = 0; k < KW; ++k)
        #pragma unroll
        for (int c = 0; c < LCH; ++c)
            cw[k][c] = ((const float4*)(conv_w + c * (KW * EE) + k * EE))[lane];
    __syncthreads();

    #pragma unroll
    for (int wi = 0; wi < 4; ++wi) {
        int w = wv + wi * 4;
        float acc[LCH] = {0.f, 0.f, 0.f, 0.f};
        #pragma unroll
        for (int k = 0; k < KW; ++k) {
            float4 v = ce[(w + k) * 64 + lane];
            #pragma unroll
            for (int c = 0; c < LCH; ++c)
                acc[c] += v.x * cw[k][c].x + v.y * cw[k][c].y +
                          v.z * cw[k][c].z + v.w * cw[k][c].w;
        }
        #pragma unroll
        for (int c = 0; c < LCH; ++c) {
            float s = wave_reduce_sum(acc[c]);
            if (lane == 0) phi[w * LCH + c] = s;
        }
    }
    __syncthreads();
    if (t < LCH) {
        float m = -1e30f;
        for (int w = 0; w < WN; ++w) m = fmaxf(m, phi[w * LCH + t]);
        charrep[t] = m + conv_b[t];
    }
    __syncthreads();

    const int word = sent[r];
    X[(size_t)r * KPAD + t] = f2bf(word_emb[(size_t)word * EE + t]);
    if (t < LCH) X[(size_t)r * KPAD + EE + t] = f2bf(charrep[t]);
    if (t >= 228) X[(size_t)r * KPAD + 32 + t] = (short)0;
}

// ---- input GEMM -> ginP[t][g][bl][gate][uu][b16] (coalesced per-step read) --
__global__ __launch_bounds__(256) void gemm_in_kernel(
    const short* __restrict__ X, const short* __restrict__ Wih,
    const float* __restrict__ b_ih, const float* __restrict__ b_hh,
    short* __restrict__ ginP)
{
    const int tid = threadIdx.x;
    const int l = tid & 63, wv = tid >> 6;
    const int r0 = blockIdx.x * 64;          // rows = t*64 + b
    const int n0 = blockIdx.y * 128 + wv * 32;
    const int lr = l & 15, lh = l >> 4;

    floatx4 acc[4][2];
    #pragma unroll
    for (int m = 0; m < 4; ++m)
        #pragma unroll
        for (int n = 0; n < 2; ++n) acc[m][n] = (floatx4)0.f;

    const short* Xb = X + (size_t)(r0 + lr) * KPAD + lh * 8;
    const short* Wb = Wih + (size_t)(n0 + lr) * KPAD + lh * 8;

    #pragma unroll
    for (int k0 = 0; k0 < KPAD; k0 += 32) {
        short8 a0 = *(const short8*)(Xb + k0);
        short8 a1 = *(const short8*)(Xb + 16 * KPAD + k0);
        short8 a2 = *(const short8*)(Xb + 32 * KPAD + k0);
        short8 a3 = *(const short8*)(Xb + 48 * KPAD + k0);
        short8 b0 = *(const short8*)(Wb + k0);
        short8 b1 = *(const short8*)(Wb + 16 * KPAD + k0);
        acc[0][0] = __builtin_amdgcn_mfma_f32_16x16x32_bf16(a0, b0, acc[0][0], 0, 0, 0);
        acc[1][0] = __builtin_amdgcn_mfma_f32_16x16x32_bf16(a1, b0, acc[1][0], 0, 0, 0);
        acc[2][0] = __builtin_amdgcn_mfma_f32_16x16x32_bf16(a2, b0, acc[2][0], 0, 0, 0);
        acc[3][0] = __builtin_amdgcn_mfma_f32_16x16x32_bf16(a3, b0, acc[3][0], 0, 0, 0);
        acc[0][1] = __builtin_amdgcn_mfma_f32_16x16x32_bf16(a0, b1, acc[0][1], 0, 0, 0);
        acc[1][1] = __builtin_amdgcn_mfma_f32_16x16x32_bf16(a1, b1, acc[1][1], 0, 0, 0);
        acc[2][1] = __builtin_amdgcn_mfma_f32_16x16x32_bf16(a2, b1, acc[2][1], 0, 0, 0);
        acc[3][1] = __builtin_amdgcn_mfma_f32_16x16x32_bf16(a3, b1, acc[3][1], 0, 0, 0);
    }
    // rows r0+m*16+lh*4+q: t=blockIdx.x, g=m, b16=lh*4+q
    #pragma unroll
    for (int m = 0; m < 4; ++m)
        #pragma unroll
        for (int n = 0; n < 2; ++n) {
            int col = n0 + n * 16 + lr;            // gate-unit index 0..4095
            float bias = b_ih[col] + b_hh[col];
            short4v pack;
            #pragma unroll
            for (int q = 0; q < 4; ++q) pack[q] = f2bf(acc[m][n][q] + bias);
            int w_ = col >> 10, bl_ = (col >> 4) & 63, uu_ = col & 15;
            size_t addr = ((((size_t)(blockIdx.x * GRP + m) * 64 + bl_) * 4 + w_) * 16
                           + uu_) * 16 + lh * 4;
            *(short4v*)(ginP + addr) = pack;
        }
}

// ---------------- persistent LSTM: self-validating seq-tagged h exchange -----
// 256 blocks x 512 thr. Block = (g = bid>>6, bl = bid&63: units bl*16..+15).
// Wave w owns K-chunk w*128. h stored as dwords (bf16<<16)|seq via sc0sc1;
// consumers retry-load until all seq tags match — no flags, no fences.
__global__ __launch_bounds__(512, 1) void lstm_seq_kernel(
    unsigned* __restrict__ hst, const short* __restrict__ wpk,
    const short* __restrict__ ginP)
{
    __shared__ __align__(16) float lds_g[8][4][16][20];
    __shared__ __align__(16) unsigned hbuf32[16][20];

    const int tid = threadIdx.x;
    const int l = tid & 63;
    const int w = tid >> 6;             // wave 0..7 = K-chunk id
    const int g  = blockIdx.x >> 6;     // batch group (16 batches)
    const int bl = blockIdx.x & 63;     // unit block (16 units)

    // resident weights: wave w holds (4 gates x 16 units) x K-chunk w*128
    short8 barr[4][4];
    {
        const short* wb = wpk + ((size_t)(bl * 8 + w) * 16) * 512 + l * 8;
        #pragma unroll
        for (int tl = 0; tl < 4; ++tl)
            #pragma unroll
            for (int s = 0; s < 4; ++s)
                barr[tl][s] = *(const short8*)(wb + (tl * 4 + s) * 512);
    }

    const int b16 = tid & 15;           // epilogue: batch (tid<256)
    const int uu  = (tid >> 4) & 15;    // epilogue: unit
    float c = 0.f;

    // this thread's h-store segment (8 per wave): seg = w*8 + (l&7), lanes l<8
    const int seg = w * 8 + (l & 7);
    const int s_lr = seg & 15, s_hl = (seg >> 4) & 1, s_eh = seg >> 5;
    const int s_ll = (2 * (bl & 1) + s_hl) * 16 + s_lr;
    const size_t s_off = (size_t)g * 16384 + (size_t)(bl >> 1) * 512 + s_ll * 8 + s_eh * 4;

    float gv[4] = {0.f, 0.f, 0.f, 0.f};
    if (tid < 256) {
        const short* gb = ginP + (((size_t)g * 64 + bl) * 4) * 256 + uu * 16 + b16;
        #pragma unroll
        for (int q = 0; q < 4; ++q) gv[q] = bf2f(gb[q * 256]);
    }

    for (int t = 0; t < PP; ++t) {
        if (t > 0) {
            // retry-load this wave's 4 chunks until every dword's seq == t
            const unsigned* A = hst + (size_t)(t - 1) * HSTEP32 + g * 16384
                                + (w * 4) * 512 + l * 8;
            int4v d[8];
            int ok;
            do {
                #pragma unroll
                for (int s = 0; s < 4; ++s) {
                    asm volatile("global_load_dwordx4 %0, %1, off sc0 sc1"
                                 : "=v"(d[2 * s]) : "v"(A + s * 512) : "memory");
                    asm volatile("global_load_dwordx4 %0, %1, off sc0 sc1"
                                 : "=v"(d[2 * s + 1]) : "v"(A + s * 512 + 4) : "memory");
                }
                asm volatile("s_waitcnt vmcnt(0)" ::: "memory");
                __builtin_amdgcn_sched_barrier(0);
                ok = 1;
                #pragma unroll
                for (int i = 0; i < 8; ++i)
                    #pragma unroll
                    for (int j = 0; j < 4; ++j)
                        ok &= ((((unsigned)d[i][j]) & 0xFFFFu) == (unsigned)t);
                ok = __all(ok);
                if (!ok) __builtin_amdgcn_s_sleep(2);
            } while (!ok);

            floatx4 acc[4];
            #pragma unroll
            for (int tl = 0; tl < 4; ++tl) acc[tl] = (floatx4)0.f;
            #pragma unroll
            for (int s = 0; s < 4; ++s) {
                int4v pk;
                pk[0] = (int)((((unsigned)d[2*s][0]) >> 16)   | (((unsigned)d[2*s][1])   & 0xFFFF0000u));
                pk[1] = (int)((((unsigned)d[2*s][2]) >> 16)   | (((unsigned)d[2*s][3])   & 0xFFFF0000u));
                pk[2] = (int)((((unsigned)d[2*s+1][0]) >> 16) | (((unsigned)d[2*s+1][1]) & 0xFFFF0000u));
                pk[3] = (int)((((unsigned)d[2*s+1][2]) >> 16) | (((unsigned)d[2*s+1][3]) & 0xFFFF0000u));
                short8 av = __builtin_bit_cast(short8, pk);
                #pragma unroll
                for (int tl = 0; tl < 4; ++tl)
                    acc[tl] = __builtin_amdgcn_mfma_f32_16x16x32_bf16(
                        av, barr[tl][s], acc[tl], 0, 0, 0);
            }
            #pragma unroll
            for (int tl = 0; tl < 4; ++tl)
                *(floatx4*)&lds_g[w][tl][l & 15][(l >> 4) * 4] = acc[tl];
            __syncthreads();
        }

        if (tid < 256) {
            float s0 = gv[0], s1 = gv[1], s2 = gv[2], s3 = gv[3];
            if (t > 0) {
                #pragma unroll
                for (int w2 = 0; w2 < 8; ++w2) {
                    s0 += lds_g[w2][0][uu][b16];
                    s1 += lds_g[w2][1][uu][b16];
                    s2 += lds_g[w2][2][uu][b16];
                    s3 += lds_g[w2][3][uu][b16];
                }
            }
            float i_ = sigf(s0), f_ = sigf(s1), g_ = tanhfast(s2), o_ = sigf(s3);
            c = f_ * c + i_ * g_;
            unsigned hd = (((unsigned)(unsigned short)f2bf(o_ * tanhfast(c))) << 16)
                          | (unsigned)(t + 1);
            hbuf32[b16][uu] = hd;

            // prefetch gin for t+1 (hidden under store/retry)
            if (t + 1 < PP) {
                const short* gb = ginP + (((size_t)(t + 1) * GRP + g) * 64 + bl) * 1024
                                  + uu * 16 + b16;
                #pragma unroll
                for (int q = 0; q < 4; ++q) gv[q] = bf2f(gb[q * 256]);
            }
        }
        __syncthreads();

        // seq-tagged h store, 8 lanes per wave, fire-and-forget (sc0 sc1 -> IF)
        if ((l & 56) == 0) {   // lanes 0..7 of each wave
            int4v hv = *(const int4v*)&hbuf32[s_lr][s_hl * 8 + s_eh * 4];
            unsigned* hp = hst + (size_t)t * HSTEP32 + s_off;
            asm volatile("global_store_dwordx4 %0, %1, off sc0 sc1"
                         :: "v"(hp), "v"(hv) : "memory");
        }
    }
}

// ---------------- tag head: out = hs·out_w^T + out_b (MFMA) ------------------
// 80 blocks x 4 waves; block = timestep t, wave wv = 16 tags, m-tile = group
__global__ __launch_bounds__(256) void tag_kernel(
    const unsigned* __restrict__ hst, const short* __restrict__ outw_bf,
    const float* __restrict__ out_b, float* __restrict__ out)
{
    const int tid = threadIdx.x;
    const int l = tid & 63, wv = tid >> 6;
    const int t = blockIdx.x;
    const int n0 = wv * 16;
    const int lr = l & 15, lh = l >> 4;

    const unsigned* At = hst + (size_t)t * HSTEP32;
    const short* Bw = outw_bf + (size_t)(n0 + lr) * HH + lh * 8;

    floatx4 acc[4];
    #pragma unroll
    for (int m = 0; m < 4; ++m) acc[m] = (floatx4)0.f;

    #pragma unroll 4
    for (int kk = 0; kk < 32; ++kk) {
        short8 b = *(const short8*)(Bw + kk * 32);
        #pragma unroll
        for (int m = 0; m < 4; ++m) {
            const unsigned* ap = At + m * 16384 + kk * 512 + l * 8;
            int4v d0 = *(const int4v*)(ap);
            int4v d1 = *(const int4v*)(ap + 4);
            int4v pk;
            pk[0] = (int)((((unsigned)d0[0]) >> 16) | (((unsigned)d0[1]) & 0xFFFF0000u));
            pk[1] = (int)((((unsigned)d0[2]) >> 16) | (((unsigned)d0[3]) & 0xFFFF0000u));
            pk[2] = (int)((((unsigned)d1[0]) >> 16) | (((unsigned)d1[1]) & 0xFFFF0000u));
            pk[3] = (int)((((unsigned)d1[2]) >> 16) | (((unsigned)d1[3]) & 0xFFFF0000u));
            short8 a = __builtin_bit_cast(short8, pk);
            acc[m] = __builtin_amdgcn_mfma_f32_16x16x32_bf16(a, b, acc[m], 0, 0, 0);
        }
    }
    int col = n0 + lr;
    if (col < TAGS) {
        float bias = out_b[col];
        #pragma unroll
        for (int m = 0; m < 4; ++m)
            #pragma unroll
            for (int q = 0; q < 4; ++q) {
                int row = t * 64 + m * 16 + lh * 4 + q;   // flat row r = t*64+b
                out[(size_t)row * TAGS + col] = acc[m][q] + bias;
            }
    }
}

// ---------------- log_softmax over the P axis, in place ----------------------
__global__ __launch_bounds__(256) void logsoftmax_kernel(float* __restrict__ out)
{
    const int tid = threadIdx.x;
    const int lane = tid & 63;
    const int pair = blockIdx.x * 4 + (tid >> 6);
    if (pair >= BB * TAGS) return;
    const int bb = pair / TAGS, g = pair % TAGS;
    float* base = out + (size_t)bb * PP * TAGS + g;
    float v0 = base[lane * TAGS];
    float v1 = (lane < PP - 64) ? base[(lane + 64) * TAGS] : -1e30f;
    float m = fmaxf(v0, v1);
    for (int off = 32; off > 0; off >>= 1) m = fmaxf(m, __shfl_xor(m, off, 64));
    float s = __expf(v0 - m) + ((lane < PP - 64) ? __expf(v1 - m) : 0.f);
    s = wave_reduce_sum(s);
    float lz = m + __logf(s);
    base[lane * TAGS] = v0 - lz;
    if (lane < PP - 64) base[(lane + 64) * TAGS] = v1 - lz;
}

extern "C" void kernel_launch(void* const* d_in, const int* in_sizes, int n_in,
                              void* d_out, int out_size, void* d_ws, size_t ws_size,
                              hipStream_t stream)
{
    const int*   sent     = (const int*)d_in[0];
    const int*   chars    = (const int*)d_in[1];
    const float* word_emb = (const float*)d_in[2];
    const float* char_emb = (const float*)d_in[3];
    const float* conv_w   = (const float*)d_in[4];
    const float* conv_b   = (const float*)d_in[5];
    const float* w_ih     = (const float*)d_in[6];
    const float* w_hh     = (const float*)d_in[7];
    const float* b_ih     = (const float*)d_in[8];
    const float* b_hh     = (const float*)d_in[9];
    const float* out_w    = (const float*)d_in[10];
    const float* out_b    = (const float*)d_in[11];
    float* out = (float*)d_out;

    short* X_bf     = (short*)d_ws;                            // 5120*288
    short* wih_bf   = X_bf + (size_t)ROWS * KPAD;              // 4096*288
    short* wpk      = wih_bf + (size_t)NG * KPAD;              // 4096*1024 (frag-major)
    short* outw_bf  = wpk + (size_t)NG * HH;                   // 64*1024
    short* ginP     = outw_bf + (size_t)64 * HH;               // 4096*5120
    unsigned* hst32 = (unsigned*)(ginP + (size_t)NG * ROWS);   // 80*HSTEP32 dwords

    hipLaunchKernelGGL(prep_kernel, dim3(2048), dim3(256), 0, stream,
                       w_ih, w_hh, out_w, wih_bf, wpk, outw_bf, hst32);
    hipLaunchKernelGGL(embed_kernel, dim3(ROWS), dim3(256), 0, stream,
                       sent, chars, word_emb, char_emb, conv_w, conv_b, X_bf);
    hipLaunchKernelGGL(gemm_in_kernel, dim3(ROWS / 64, NG / 128), dim3(256), 0, stream,
                       X_bf, wih_bf, b_ih, b_hh, ginP);
    {
        void* kargs[3] = { (void*)&hst32, (void*)&wpk, (void*)&ginP };
        hipLaunchCooperativeKernel((void*)lstm_seq_kernel, dim3(NBLK), dim3(512),
                                   kargs, 0, stream);
    }
    hipLaunchKernelGGL(tag_kernel, dim3(PP), dim3(256), 0, stream,
                       hst32, outw_bf, out_b, out);
    hipLaunchKernelGGL(logsoftmax_kernel, dim3((BB * TAGS + 3) / 4), dim3(256), 0, stream,
                       out);
}